// Round 11
// baseline (812.413 us; speedup 1.0000x reference)
//
#include <hip/hip_runtime.h>
#include <hip/hip_bf16.h>
#include <stdint.h>
#include <stddef.h>

#define HW 262144          // 512*512
#define EPSF 1e-5f
#define NBLK 1024

typedef __hip_bfloat16 bf16;

__device__ __forceinline__ float us2f(uint32_t u){
  union { uint32_t i; float f; } c; c.i = u << 16; return c.f;
}
__device__ __forceinline__ ushort f2bu(float v){
  union { bf16 h; ushort u; } c; c.h = __float2bfloat16(v); return c.u;
}
__device__ __forceinline__ float lrelu(float v){ return v > 0.0f ? v : 0.01f * v; }
__device__ __forceinline__ uint32_t umax2(uint32_t a, uint32_t b){ return a > b ? a : b; }

// ---------------------------------------------------------------------------
// K0a: quantize x to level k = rint(x*255/16), reflect-padded u8 plane
// ---------------------------------------------------------------------------
__global__ __launch_bounds__(256) void k_quant_pad(const float* __restrict__ x,
                                                   uint8_t* __restrict__ qpad){
  int idx = blockIdx.x * 256 + threadIdx.x;
  if (idx >= 6 * 522 * 522) return;
  int pw = idx % 522; int t = idx / 522; int ph = t % 522; int img = t / 522;
  int h = ph - 5; h = h < 0 ? -h : h; if (h > 511) h = 1022 - h;
  int w = pw - 5; w = w < 0 ? -w : w; if (w > 511) w = 1022 - w;
  float v = x[img * HW + h * 512 + w];
  int k = (int)rintf((v * 255.0f) / 16.0f);
  qpad[img * (522 * 528) + ph * 528 + pw] = (uint8_t)k;
}

// ---------------------------------------------------------------------------
// K0b: 11x11 mode filter (LDS tile, rolled loops to avoid VGPR spill — r4/r5).
// ---------------------------------------------------------------------------
__global__ __launch_bounds__(256) void k_mode(const uint8_t* __restrict__ qpad,
                                              uint8_t* __restrict__ xm){
  __shared__ uint8_t tile[14 * 528];
  int tid = threadIdx.x;
  int img = blockIdx.x >> 7;
  int h0  = (blockIdx.x & 127) << 2;
  {
    const uint4* g4 = (const uint4*)(qpad + img * (522 * 528) + h0 * 528);
    uint4* t4 = (uint4*)tile;
    t4[tid] = g4[tid];
    if (tid < 206) t4[tid + 256] = g4[tid + 256];
  }
  __syncthreads();
  int r4 = tid >> 6;
  int w0 = (tid & 63) << 3;
  const uint8_t* base = tile + r4 * 528 + w0;
  uint32_t c0 = 0, c1 = 0, c2 = 0, c3 = 0, c4 = 0;
#define HINC(q) { uint32_t inc_ = 1u << (((q) & 3u) << 3); uint32_t rr_ = (q) >> 2; \
    c0 += (rr_==0u)?inc_:0u; c1 += (rr_==1u)?inc_:0u; c2 += (rr_==2u)?inc_:0u; \
    c3 += (rr_==3u)?inc_:0u; c4 += (rr_==4u)?inc_:0u; }
#define HDEC(q) { uint32_t inc_ = 1u << (((q) & 3u) << 3); uint32_t rr_ = (q) >> 2; \
    c0 -= (rr_==0u)?inc_:0u; c1 -= (rr_==1u)?inc_:0u; c2 -= (rr_==2u)?inc_:0u; \
    c3 -= (rr_==3u)?inc_:0u; c4 -= (rr_==4u)?inc_:0u; }
  #pragma unroll 1
  for (int r = 0; r < 11; ++r){
    const uint8_t* row = base + r * 528;
    #pragma unroll
    for (int j = 0; j < 11; ++j){ uint32_t q = row[j]; HINC(q); }
  }
  uint64_t packed = 0;
  #pragma unroll 1
  for (int s = 0; s < 8; ++s){
#define KEY(reg, sh, l) (((((reg) >> (sh)) & 0xffu) << 5) | (16u - (uint32_t)(l)))
    uint32_t m0 = umax2(umax2(KEY(c0,0,0),  KEY(c0,8,1)),  umax2(KEY(c0,16,2),  KEY(c0,24,3)));
    uint32_t m1 = umax2(umax2(KEY(c1,0,4),  KEY(c1,8,5)),  umax2(KEY(c1,16,6),  KEY(c1,24,7)));
    uint32_t m2 = umax2(umax2(KEY(c2,0,8),  KEY(c2,8,9)),  umax2(KEY(c2,16,10), KEY(c2,24,11)));
    uint32_t m3 = umax2(umax2(KEY(c3,0,12), KEY(c3,8,13)), umax2(KEY(c3,16,14), KEY(c3,24,15)));
    uint32_t m  = umax2(umax2(umax2(m0, m1), umax2(m2, m3)), KEY(c4,0,16));
#undef KEY
    uint32_t lvl = 16u - (m & 31u);
    packed |= ((uint64_t)lvl) << (8 * s);
    if (s < 7){
      #pragma unroll
      for (int r = 0; r < 11; ++r){
        uint32_t qo = base[r * 528 + s];      HDEC(qo);
        uint32_t qn = base[r * 528 + s + 11]; HINC(qn);
      }
    }
  }
#undef HINC
#undef HDEC
  *(uint64_t*)(xm + img * HW + (h0 + r4) * 512 + w0) = packed;
}

// ---------------------------------------------------------------------------
// block reduction of per-thread su[16]/sq[16] -> partials[block][32]
// ---------------------------------------------------------------------------
__device__ __forceinline__ void reduce16(float* su, float* sq, float* __restrict__ partials){
  __shared__ float lsum[32];
  int tid = threadIdx.x;
  if (tid < 32) lsum[tid] = 0.0f;
  __syncthreads();
  #pragma unroll
  for (int o = 0; o < 16; ++o){
    float s = su[o], q = sq[o];
    #pragma unroll
    for (int off = 32; off >= 1; off >>= 1){
      s += __shfl_xor(s, off);
      q += __shfl_xor(q, off);
    }
    if ((tid & 63) == 0){ atomicAdd(&lsum[o], s); atomicAdd(&lsum[16 + o], q); }
  }
  __syncthreads();
  if (tid < 32) partials[blockIdx.x * 32 + tid] = lsum[tid];
}

// ---------------------------------------------------------------------------
// K1: stats of p1 = conv1x1(xm). 4 px/thread. grid 512 x 256.
// ---------------------------------------------------------------------------
__global__ __launch_bounds__(256) void k_stats1(const uint8_t* __restrict__ xm,
                                                const float* __restrict__ w1,
                                                const float* __restrict__ b1,
                                                float* __restrict__ partials){
  int t0 = (blockIdx.x * 256 + threadIdx.x) << 2;
  int b = t0 >> 18, hw = t0 & (HW - 1);
  uint32_t q0 = *(const uint32_t*)(xm + (b * 3 + 0) * HW + hw);
  uint32_t q1 = *(const uint32_t*)(xm + (b * 3 + 1) * HW + hw);
  uint32_t q2 = *(const uint32_t*)(xm + (b * 3 + 2) * HW + hw);
  float su[16], sq[16];
  #pragma unroll
  for (int o = 0; o < 16; ++o){ su[o] = 0.0f; sq[o] = 0.0f; }
  #pragma unroll
  for (int px = 0; px < 4; ++px){
    float x0 = (float)((q0 >> (8 * px)) & 0xffu) * 0.0625f;
    float x1 = (float)((q1 >> (8 * px)) & 0xffu) * 0.0625f;
    float x2 = (float)((q2 >> (8 * px)) & 0xffu) * 0.0625f;
    #pragma unroll
    for (int o = 0; o < 16; ++o){
      float v = b1[o] + w1[o*3]*x0 + w1[o*3+1]*x1 + w1[o*3+2]*x2;
      su[o] += v; sq[o] += v * v;
    }
  }
  reduce16(su, sq, partials);
}

// ---------------------------------------------------------------------------
// K2: recompute p1, bn1+lrelu, p2 = conv1x1, stats of p2. 4 px/thread.
// ---------------------------------------------------------------------------
__global__ __launch_bounds__(256) void k_stats2(const uint8_t* __restrict__ xm,
                                                const float* __restrict__ w1,
                                                const float* __restrict__ b1,
                                                const float* __restrict__ w2,
                                                const float* __restrict__ b2,
                                                const float* __restrict__ params,
                                                float* __restrict__ partials){
  int t0 = (blockIdx.x * 256 + threadIdx.x) << 2;
  int b = t0 >> 18, hw = t0 & (HW - 1);
  uint32_t q0 = *(const uint32_t*)(xm + (b * 3 + 0) * HW + hw);
  uint32_t q1 = *(const uint32_t*)(xm + (b * 3 + 1) * HW + hw);
  uint32_t q2 = *(const uint32_t*)(xm + (b * 3 + 2) * HW + hw);
  float tv[4][16];
  #pragma unroll
  for (int px = 0; px < 4; ++px){
    float x0 = (float)((q0 >> (8 * px)) & 0xffu) * 0.0625f;
    float x1 = (float)((q1 >> (8 * px)) & 0xffu) * 0.0625f;
    float x2 = (float)((q2 >> (8 * px)) & 0xffu) * 0.0625f;
    #pragma unroll
    for (int o = 0; o < 16; ++o){
      float v = b1[o] + w1[o*3]*x0 + w1[o*3+1]*x1 + w1[o*3+2]*x2;
      tv[px][o] = lrelu(v * params[o] + params[16 + o]);
    }
  }
  float su[16], sq[16];
  #pragma unroll
  for (int o = 0; o < 16; ++o){ su[o] = 0.0f; sq[o] = 0.0f; }
  #pragma unroll
  for (int o = 0; o < 16; ++o){
    #pragma unroll
    for (int px = 0; px < 4; ++px){
      float acc = b2[o];
      #pragma unroll
      for (int c = 0; c < 16; ++c) acc = fmaf(w2[o*16 + c], tv[px][c], acc);
      su[o] += acc; sq[o] += acc * acc;
    }
  }
  reduce16(su, sq, partials);
}

// ---------------------------------------------------------------------------
// K3: recompute p2, bn2+lrelu, write p (bf16). Also resets the barrier ctr.
// ---------------------------------------------------------------------------
__global__ __launch_bounds__(256) void k_prep(const uint8_t* __restrict__ xm,
                                              const float* __restrict__ w1,
                                              const float* __restrict__ b1,
                                              const float* __restrict__ w2,
                                              const float* __restrict__ b2,
                                              const float* __restrict__ params,
                                              bf16* __restrict__ p,
                                              unsigned* __restrict__ barcnt){
  if (blockIdx.x == 0 && threadIdx.x == 0) *barcnt = 0u;
  int t0 = (blockIdx.x * 256 + threadIdx.x) << 2;
  int b = t0 >> 18, hw = t0 & (HW - 1);
  uint32_t q0 = *(const uint32_t*)(xm + (b * 3 + 0) * HW + hw);
  uint32_t q1 = *(const uint32_t*)(xm + (b * 3 + 1) * HW + hw);
  uint32_t q2 = *(const uint32_t*)(xm + (b * 3 + 2) * HW + hw);
  float tv[4][16];
  #pragma unroll
  for (int px = 0; px < 4; ++px){
    float x0 = (float)((q0 >> (8 * px)) & 0xffu) * 0.0625f;
    float x1 = (float)((q1 >> (8 * px)) & 0xffu) * 0.0625f;
    float x2 = (float)((q2 >> (8 * px)) & 0xffu) * 0.0625f;
    #pragma unroll
    for (int o = 0; o < 16; ++o){
      float v = b1[o] + w1[o*3]*x0 + w1[o*3+1]*x1 + w1[o*3+2]*x2;
      tv[px][o] = lrelu(v * params[o] + params[16 + o]);
    }
  }
  #pragma unroll
  for (int o = 0; o < 16; ++o){
    uint32_t w01 = 0, w23 = 0;
    #pragma unroll
    for (int px = 0; px < 4; ++px){
      float acc = b2[o];
      #pragma unroll
      for (int c = 0; c < 16; ++c) acc = fmaf(w2[o*16 + c], tv[px][c], acc);
      float v = lrelu(acc * params[32 + o] + params[48 + o]);
      uint32_t bits = (uint32_t)f2bu(v);
      if (px == 0) w01 = bits;
      else if (px == 1) w01 |= bits << 16;
      else if (px == 2) w23 = bits;
      else w23 |= bits << 16;
    }
    uint2 ov; ov.x = w01; ov.y = w23;
    *(uint2*)((ushort*)p + (b * 16 + o) * HW + hw) = ov;
  }
}

// ---------------------------------------------------------------------------
// finalize: prepare-stage BN (512-block x 32 partials layout), grid 1
// ---------------------------------------------------------------------------
__global__ __launch_bounds__(256) void k_fin_prep(const float* __restrict__ partials,
                                                  const float* __restrict__ g,
                                                  const float* __restrict__ bb,
                                                  float* __restrict__ params,
                                                  int offS, int offT){
  int tid = threadIdx.x;
  int o = tid & 15, c = tid >> 4;
  double S = 0.0, Q = 0.0;
  for (int i = c * 32; i < (c + 1) * 32; ++i){
    S += (double)partials[i * 32 + o];
    Q += (double)partials[i * 32 + 16 + o];
  }
  __shared__ double lS[256], lQ[256];
  lS[tid] = S; lQ[tid] = Q; __syncthreads();
  for (int st = 8; st >= 1; st >>= 1){
    if (c < st){ lS[tid] += lS[tid + st * 16]; lQ[tid] += lQ[tid + st * 16]; }
    __syncthreads();
  }
  if (tid < 16){
    double m = lS[tid] / 524288.0;
    double v = lQ[tid] / 524288.0 - m * m;
    float sc = g[tid] / sqrtf((float)v + EPSF);
    params[offS + tid] = sc;
    params[offT + tid] = bb[tid] - (float)m * sc;
  }
}

// ---------------------------------------------------------------------------
// helpers for the persistent loop kernel
// ---------------------------------------------------------------------------
__device__ __forceinline__ void load_row10(const ushort* __restrict__ rp, int w0, float* v){
  uint4 cc = *(const uint4*)(rp + w0);
  uint32_t l = (w0 == 0)   ? 0u : (uint32_t)rp[w0 - 1];
  uint32_t r = (w0 == 504) ? 0u : (uint32_t)rp[w0 + 8];
  v[0] = us2f(l);
  v[1] = us2f(cc.x & 0xffffu); v[2] = us2f(cc.x >> 16);
  v[3] = us2f(cc.y & 0xffffu); v[4] = us2f(cc.y >> 16);
  v[5] = us2f(cc.z & 0xffffu); v[6] = us2f(cc.z >> 16);
  v[7] = us2f(cc.w & 0xffffu); v[8] = us2f(cc.w >> 16);
  v[9] = us2f(r);
}

// wave-butterfly sum of channel f over a [1024][2] partials buffer (64 entries)
__device__ __forceinline__ void chan_sum64(const float* __restrict__ P, int f, int lane,
                                           double& S, double& Q){
  int b = lane >> 5, rgx = lane & 31;
  int blk = ((b * 16 + f) << 5) + rgx;
  S = (double)P[blk * 2];
  Q = (double)P[blk * 2 + 1];
  #pragma unroll
  for (int off = 32; off >= 1; off >>= 1){
    S += __shfl_xor(S, off);
    Q += __shfl_xor(Q, off);
  }
}

// device-wide barrier: monotone counter, all NBLK blocks co-resident
// (__launch_bounds__(256,4) caps VGPR at 128 -> 4 blocks/CU x 256 CU = 1024).
// __threadfence = agent-scope release/acquire (L2 writeback/invalidate, G16).
__device__ __forceinline__ void gbar(unsigned* cnt, unsigned target){
  __syncthreads();                       // drains vmcnt before barrier
  if (threadIdx.x == 0){
    __threadfence();
    atomicAdd(cnt, 1u);
    while (atomicAdd(cnt, 0u) < target) __builtin_amdgcn_s_sleep(8);
    __threadfence();
  }
  __syncthreads();
}

// ---------------------------------------------------------------------------
// PERSISTENT loop kernel: conv-stats prologue, 5 BN+conv iterations, final
// assembly — one launch, 6 device-wide barriers. grid 1024 x 256.
// Block = 16 rows of one plane; strip = 18 rows in LDS.
// ---------------------------------------------------------------------------
__global__ __launch_bounds__(256, 4) void k_loop(
    const bf16* __restrict__ p, const float* __restrict__ dw,
    const float* __restrict__ gd, const float* __restrict__ bd,
    bf16* __restrict__ cbuf_a, bf16* __restrict__ cbuf_b,
    bf16* d0, bf16* d1, bf16* d2, bf16* d3, bf16* d4,
    float* __restrict__ P1a, float* __restrict__ P1b, float* __restrict__ P2,
    const float* __restrict__ ww, const float* __restrict__ gw,
    const float* __restrict__ bw, const float* __restrict__ wh,
    const float* __restrict__ gh, const float* __restrict__ bh,
    float* __restrict__ out, unsigned* __restrict__ barcnt){
  __shared__ ushort strip[18][512];      // 18 KB
  __shared__ float acc4[4];
  __shared__ float sparams[20];
  __shared__ bf16* sdbuf[5];
  int bid = blockIdx.x;
  int tid = threadIdx.x;
  int plane = bid >> 5, rg = bid & 31;   // 32 planes x 32 groups of 16 rows
  int f = plane & 15;
  int h0 = rg << 4;
  int w0 = (tid & 63) << 3;
  int sr0 = tid >> 6;                    // 0..3
  if (tid == 0){ sdbuf[0]=d0; sdbuf[1]=d1; sdbuf[2]=d2; sdbuf[3]=d3; sdbuf[4]=d4; }
  if (tid < 4) acc4[tid] = 0.0f;
  float wf[9];
  #pragma unroll
  for (int i = 0; i < 9; ++i) wf[i] = dw[f * 9 + i];

  // ---- phase -1: stage p strip, c0 = conv(p) -> cbuf_a, stats -> P1a ----
  {
    const ushort* pl = (const ushort*)p + plane * HW;
    #pragma unroll
    for (int rr = 0; rr < 4; ++rr){
      int row = h0 + rr * 4 + sr0;
      uint4 v = *(const uint4*)(pl + row * 512 + w0);
      *(uint4*)&strip[1 + rr * 4 + sr0][w0] = v;
    }
    if (tid < 128){
      int hh = (tid < 64) ? h0 - 1 : h0 + 16;
      int si = (tid < 64) ? 0 : 17;
      int wh0 = (tid & 63) << 3;
      uint4 v; v.x = 0; v.y = 0; v.z = 0; v.w = 0;
      if ((unsigned)hh < 512u) v = *(const uint4*)(pl + hh * 512 + wh0);
      *(uint4*)&strip[si][wh0] = v;
    }
    __syncthreads();
    float s1 = 0.0f, q1 = 0.0f;
    ushort* ca = (ushort*)cbuf_a + plane * HW;
    #pragma unroll
    for (int rr = 0; rr < 4; ++rr){
      int sr = 1 + rr * 4 + sr0;
      float v[3][10];
      #pragma unroll
      for (int dy = 0; dy < 3; ++dy) load_row10(&strip[sr - 1 + dy][0], w0, v[dy]);
      uint32_t cb[4];
      #pragma unroll
      for (int k = 0; k < 8; ++k){
        float acc = 0.0f;
        #pragma unroll
        for (int dy = 0; dy < 3; ++dy)
          #pragma unroll
          for (int dx = 0; dx < 3; ++dx)
            acc = fmaf(wf[dy*3 + dx], v[dy][k + dx], acc);
        s1 += acc; q1 += acc * acc;
        uint32_t bits = (uint32_t)f2bu(acc);
        if ((k & 1) == 0) cb[k >> 1] = bits; else cb[k >> 1] |= bits << 16;
      }
      uint4 cv; cv.x = cb[0]; cv.y = cb[1]; cv.z = cb[2]; cv.w = cb[3];
      *(uint4*)(ca + (h0 + rr * 4 + sr0) * 512 + w0) = cv;
    }
    #pragma unroll
    for (int off = 32; off >= 1; off >>= 1){
      s1 += __shfl_xor(s1, off); q1 += __shfl_xor(q1, off);
    }
    if ((tid & 63) == 0){ atomicAdd(&acc4[0], s1); atomicAdd(&acc4[1], q1); }
    __syncthreads();
    if (tid < 2) P1a[bid * 2 + tid] = acc4[tid];
  }
  gbar(barcnt, 1 * NBLK);

  // ---- 5 loop iterations ----
  bf16* cin = cbuf_a; bf16* cot = cbuf_b;
  float* Pin = P1a; float* Pout = P1b;
  #pragma unroll 1
  for (int t = 0; t < 5; ++t){
    double S, Q;
    chan_sum64(Pin, f, tid & 63, S, Q);
    float sc, sh;
    { double m = S / 524288.0;
      double vv = Q / 524288.0 - m * m;
      sc = gd[f] / sqrtf((float)vv + EPSF);
      sh = bd[f] - (float)m * sc; }
    if (tid < 4) acc4[tid] = 0.0f;
    const ushort* cpl = (const ushort*)cin + plane * HW;
    ushort* dpl = (ushort*)sdbuf[t] + plane * HW;
    float s2 = 0.0f, q2 = 0.0f;
    #pragma unroll
    for (int rr = 0; rr < 4; ++rr){
      int row = h0 + rr * 4 + sr0;
      uint4 cv = *(const uint4*)(cpl + row * 512 + w0);
      float cf[8];
      cf[0] = us2f(cv.x & 0xffffu); cf[1] = us2f(cv.x >> 16);
      cf[2] = us2f(cv.y & 0xffffu); cf[3] = us2f(cv.y >> 16);
      cf[4] = us2f(cv.z & 0xffffu); cf[5] = us2f(cv.z >> 16);
      cf[6] = us2f(cv.w & 0xffffu); cf[7] = us2f(cv.w >> 16);
      uint32_t ob[4];
      #pragma unroll
      for (int k = 0; k < 8; ++k){
        float vv = lrelu(fmaf(cf[k], sc, sh));
        uint32_t bits = (uint32_t)f2bu(vv);
        if ((k & 1) == 0) ob[k >> 1] = bits; else ob[k >> 1] |= bits << 16;
        s2 += vv; q2 += vv * vv;
      }
      uint4 ov; ov.x = ob[0]; ov.y = ob[1]; ov.z = ob[2]; ov.w = ob[3];
      *(uint4*)(dpl + row * 512 + w0) = ov;
      *(uint4*)&strip[1 + rr * 4 + sr0][w0] = ov;
    }
    if (tid < 128){
      int hh = (tid < 64) ? h0 - 1 : h0 + 16;
      int si = (tid < 64) ? 0 : 17;
      int wh0 = (tid & 63) << 3;
      uint4 hv; hv.x = 0; hv.y = 0; hv.z = 0; hv.w = 0;
      if ((unsigned)hh < 512u){
        uint4 cv = *(const uint4*)(cpl + hh * 512 + wh0);
        float cf[8];
        cf[0] = us2f(cv.x & 0xffffu); cf[1] = us2f(cv.x >> 16);
        cf[2] = us2f(cv.y & 0xffffu); cf[3] = us2f(cv.y >> 16);
        cf[4] = us2f(cv.z & 0xffffu); cf[5] = us2f(cv.z >> 16);
        cf[6] = us2f(cv.w & 0xffffu); cf[7] = us2f(cv.w >> 16);
        uint32_t hb[4];
        #pragma unroll
        for (int k = 0; k < 8; ++k){
          float vv = lrelu(fmaf(cf[k], sc, sh));
          uint32_t bits = (uint32_t)f2bu(vv);
          if ((k & 1) == 0) hb[k >> 1] = bits; else hb[k >> 1] |= bits << 16;
        }
        hv.x = hb[0]; hv.y = hb[1]; hv.z = hb[2]; hv.w = hb[3];
      }
      *(uint4*)&strip[si][wh0] = hv;
    }
    __syncthreads();
    float s1 = 0.0f, q1 = 0.0f;
    ushort* co = (ushort*)cot + plane * HW;
    #pragma unroll
    for (int rr = 0; rr < 4; ++rr){
      int sr = 1 + rr * 4 + sr0;
      float v[3][10];
      #pragma unroll
      for (int dy = 0; dy < 3; ++dy) load_row10(&strip[sr - 1 + dy][0], w0, v[dy]);
      uint32_t cb[4];
      #pragma unroll
      for (int k = 0; k < 8; ++k){
        float acc = 0.0f;
        #pragma unroll
        for (int dy = 0; dy < 3; ++dy)
          #pragma unroll
          for (int dx = 0; dx < 3; ++dx)
            acc = fmaf(wf[dy*3 + dx], v[dy][k + dx], acc);
        s1 += acc; q1 += acc * acc;
        uint32_t bits = (uint32_t)f2bu(acc);
        if ((k & 1) == 0) cb[k >> 1] = bits; else cb[k >> 1] |= bits << 16;
      }
      if (t < 4){
        uint4 cv2; cv2.x = cb[0]; cv2.y = cb[1]; cv2.z = cb[2]; cv2.w = cb[3];
        *(uint4*)(co + (h0 + rr * 4 + sr0) * 512 + w0) = cv2;
      }
    }
    #pragma unroll
    for (int off = 32; off >= 1; off >>= 1){
      s2 += __shfl_xor(s2, off); q2 += __shfl_xor(q2, off);
      s1 += __shfl_xor(s1, off); q1 += __shfl_xor(q1, off);
    }
    if ((tid & 63) == 0){
      atomicAdd(&acc4[0], s2); atomicAdd(&acc4[1], q2);
      atomicAdd(&acc4[2], s1); atomicAdd(&acc4[3], q1);
    }
    __syncthreads();
    if (tid < 2)      P2[t * 2048 + bid * 2 + tid] = acc4[tid];
    else if (tid < 4) Pout[bid * 2 + (tid - 2)]    = acc4[tid];
    gbar(barcnt, (unsigned)(2 + t) * NBLK);
    { bf16* tm = cin; cin = cot; cot = tm; }
    { float* tp = Pin; Pin = Pout; Pout = tp; }
  }

  // ---- final assembly phase (remapped block roles) ----
  {
    int ff = bid >> 6;                   // 0..15
    int sub = bid & 63;
    int wid = tid >> 6, lane = tid & 63;
    for (int t = wid; t < 5; t += 4){
      double S, Q;
      chan_sum64(P2 + t * 2048, ff, lane, S, Q);
      if (lane == 0){
        float m = (float)(S / 524288.0);
        float vv = (float)(Q / 524288.0) - m * m;
        float sw = ww[ff] * gw[ff] / sqrtf(ww[ff] * ww[ff] * vv + EPSF);
        float tw = bw[ff] - m * sw;
        float s2p = wh[ff] * gh[ff] / sqrtf(wh[ff] * wh[ff] * vv + EPSF);
        float t2p = bh[ff] - m * s2p;
        sparams[t * 4 + 0] = sw; sparams[t * 4 + 1] = tw;
        sparams[t * 4 + 2] = s2p; sparams[t * 4 + 3] = t2p;
      }
    }
    __syncthreads();
    #pragma unroll 1
    for (int ch = 0; ch < 2; ++ch){
      int hw = sub * 4096 + tid * 16 + ch * 8;
      int fo = ff * HW + hw;
      int f1 = (16 + ff) * HW + hw;
      uint4 rp0 = *(const uint4*)((const ushort*)p + fo);
      uint4 rp1 = *(const uint4*)((const ushort*)p + f1);
      float pf[8], pg[8];
      pf[0]=us2f(rp0.x&0xffffu); pf[1]=us2f(rp0.x>>16); pf[2]=us2f(rp0.y&0xffffu); pf[3]=us2f(rp0.y>>16);
      pf[4]=us2f(rp0.z&0xffffu); pf[5]=us2f(rp0.z>>16); pf[6]=us2f(rp0.w&0xffffu); pf[7]=us2f(rp0.w>>16);
      pg[0]=us2f(rp1.x&0xffffu); pg[1]=us2f(rp1.x>>16); pg[2]=us2f(rp1.y&0xffffu); pg[3]=us2f(rp1.y>>16);
      pg[4]=us2f(rp1.z&0xffffu); pg[5]=us2f(rp1.z>>16); pg[6]=us2f(rp1.w&0xffffu); pg[7]=us2f(rp1.w>>16);
      float a00[8], a01[8], a10[8], a11[8];
      #pragma unroll
      for (int k = 0; k < 8; ++k){ a00[k]=pf[k]; a01[k]=pg[k]; a10[k]=pf[k]; a11[k]=pg[k]; }
      #pragma unroll
      for (int t = 0; t < 5; ++t){
        const ushort* dp = (const ushort*)sdbuf[t];
        uint4 ra = *(const uint4*)(dp + fo);
        uint4 rb = *(const uint4*)(dp + f1);
        float dv0[8], dv1[8];
        dv0[0]=us2f(ra.x&0xffffu); dv0[1]=us2f(ra.x>>16); dv0[2]=us2f(ra.y&0xffffu); dv0[3]=us2f(ra.y>>16);
        dv0[4]=us2f(ra.z&0xffffu); dv0[5]=us2f(ra.z>>16); dv0[6]=us2f(ra.w&0xffffu); dv0[7]=us2f(ra.w>>16);
        dv1[0]=us2f(rb.x&0xffffu); dv1[1]=us2f(rb.x>>16); dv1[2]=us2f(rb.y&0xffffu); dv1[3]=us2f(rb.y>>16);
        dv1[4]=us2f(rb.z&0xffffu); dv1[5]=us2f(rb.z>>16); dv1[6]=us2f(rb.w&0xffffu); dv1[7]=us2f(rb.w>>16);
        float sw = sparams[t*4+0], tw = sparams[t*4+1];
        float sh2 = sparams[t*4+2], th = sparams[t*4+3];
        #pragma unroll
        for (int k = 0; k < 8; ++k){
          a00[k] += lrelu(fmaf(dv0[k], sw, tw));
          a01[k] += lrelu(fmaf(dv0[k], sh2, th));
          a10[k] += lrelu(fmaf(dv1[k], sw, tw));
          a11[k] += lrelu(fmaf(dv1[k], sh2, th));
        }
      }
      #pragma unroll
      for (int half = 0; half < 2; ++half){
        float4 v0 = { a00[half*4+0], a00[half*4+1], a00[half*4+2], a00[half*4+3] };
        float4 v1 = { a01[half*4+0], a01[half*4+1], a01[half*4+2], a01[half*4+3] };
        float4 v2 = { a10[half*4+0], a10[half*4+1], a10[half*4+2], a10[half*4+3] };
        float4 v3 = { a11[half*4+0], a11[half*4+1], a11[half*4+2], a11[half*4+3] };
        *(float4*)(out + ff * HW + hw + half*4)        = v0;
        *(float4*)(out + (16 + ff) * HW + hw + half*4) = v1;
        *(float4*)(out + (32 + ff) * HW + hw + half*4) = v2;
        *(float4*)(out + (48 + ff) * HW + hw + half*4) = v3;
      }
    }
  }
}

// ---------------------------------------------------------------------------
extern "C" void kernel_launch(void* const* d_in, const int* in_sizes, int n_in,
                              void* d_out, int out_size, void* d_ws, size_t ws_size,
                              hipStream_t stream){
  (void)in_sizes; (void)n_in; (void)out_size;
  const float* x   = (const float*)d_in[0];
  const float* w1  = (const float*)d_in[1];
  const float* b1  = (const float*)d_in[2];
  const float* g1  = (const float*)d_in[3];
  const float* be1 = (const float*)d_in[4];
  const float* w2  = (const float*)d_in[5];
  const float* b2  = (const float*)d_in[6];
  const float* g2  = (const float*)d_in[7];
  const float* be2 = (const float*)d_in[8];
  const float* dw  = (const float*)d_in[9];
  const float* gd  = (const float*)d_in[10];
  const float* bd  = (const float*)d_in[11];
  const float* ww  = (const float*)d_in[12];
  const float* gw  = (const float*)d_in[13];
  const float* bw  = (const float*)d_in[14];
  const float* wh  = (const float*)d_in[15];
  const float* gh  = (const float*)d_in[16];
  const float* bh  = (const float*)d_in[17];
  float* out = (float*)d_out;

  char* ws = (char*)d_ws;
  size_t off = 0;
  auto alloc = [&](size_t sz) -> void* {
    void* ptr = ws + off;
    off = (off + sz + 4095) & ~(size_t)4095;
    return ptr;
  };
  uint8_t* qpad  = (uint8_t*)alloc((size_t)6 * 522 * 528);
  uint8_t* xm    = (uint8_t*)alloc((size_t)6 * HW);
  bf16*    p     = (bf16*)   alloc((size_t)32 * HW * 2);
  bf16*    dbuf[5];
  for (int i = 0; i < 5; ++i) dbuf[i] = (bf16*)alloc((size_t)32 * HW * 2);
  float*   Pp     = (float*)  alloc((size_t)512 * 32 * 4);
  float*   P1a    = (float*)  alloc((size_t)NBLK * 2 * 4);
  float*   P1b    = (float*)  alloc((size_t)NBLK * 2 * 4);
  float*   P2     = (float*)  alloc((size_t)5 * NBLK * 2 * 4);
  float*   params = (float*)  alloc(4096);
  unsigned* barcnt= (unsigned*)alloc(4096);
  if (ws_size < off) return;   // workspace too small: fail visibly (untouched out)

  // c-buffers in the upper 32 MB of d_out (each 32 planes * HW bf16 = 16 MB);
  // all c traffic completes before the final phase rewrites all of out.
  bf16* cbuf_a = (bf16*)(out + 8 * 1024 * 1024);
  bf16* cbuf_b = cbuf_a + (size_t)32 * HW;

  k_quant_pad<<<dim3((6*522*522 + 255)/256), dim3(256), 0, stream>>>(x, qpad);
  k_mode     <<<dim3(768), dim3(256), 0, stream>>>(qpad, xm);
  k_stats1   <<<dim3(512), dim3(256), 0, stream>>>(xm, w1, b1, Pp);
  k_fin_prep <<<dim3(1),   dim3(256), 0, stream>>>(Pp, g1, be1, params, 0, 16);
  k_stats2   <<<dim3(512), dim3(256), 0, stream>>>(xm, w1, b1, w2, b2, params, Pp);
  k_fin_prep <<<dim3(1),   dim3(256), 0, stream>>>(Pp, g2, be2, params, 32, 48);
  k_prep     <<<dim3(512), dim3(256), 0, stream>>>(xm, w1, b1, w2, b2, params, p, barcnt);
  k_loop     <<<dim3(NBLK), dim3(256), 0, stream>>>(
      p, dw, gd, bd, cbuf_a, cbuf_b,
      dbuf[0], dbuf[1], dbuf[2], dbuf[3], dbuf[4],
      P1a, P1b, P2, ww, gw, bw, wh, gh, bh, out, barcnt);
}

// Round 12
// 223.468 us; speedup vs baseline: 3.6355x; 3.6355x over previous
//
#include <hip/hip_runtime.h>
#include <hip/hip_bf16.h>
#include <stdint.h>
#include <stddef.h>

#define HW 262144          // 512*512
#define EPSF 1e-5f

typedef __hip_bfloat16 bf16;

__device__ __forceinline__ float us2f(uint32_t u){
  union { uint32_t i; float f; } c; c.i = u << 16; return c.f;
}
__device__ __forceinline__ ushort f2bu(float v){
  union { bf16 h; ushort u; } c; c.h = __float2bfloat16(v); return c.u;
}
__device__ __forceinline__ float lrelu(float v){ return v > 0.0f ? v : 0.01f * v; }
__device__ __forceinline__ uint32_t umax2(uint32_t a, uint32_t b){ return a > b ? a : b; }

// ---------------------------------------------------------------------------
// K0a: quantize x to level k = rint(x*255/16), reflect-padded u8 plane
// ---------------------------------------------------------------------------
__global__ __launch_bounds__(256) void k_quant_pad(const float* __restrict__ x,
                                                   uint8_t* __restrict__ qpad){
  int idx = blockIdx.x * 256 + threadIdx.x;
  if (idx >= 6 * 522 * 522) return;
  int pw = idx % 522; int t = idx / 522; int ph = t % 522; int img = t / 522;
  int h = ph - 5; h = h < 0 ? -h : h; if (h > 511) h = 1022 - h;
  int w = pw - 5; w = w < 0 ? -w : w; if (w > 511) w = 1022 - w;
  float v = x[img * HW + h * 512 + w];
  int k = (int)rintf((v * 255.0f) / 16.0f);
  qpad[img * (522 * 528) + ph * 528 + pw] = (uint8_t)k;
}

// ---------------------------------------------------------------------------
// K0b: 11x11 mode filter (LDS tile, rolled loops to avoid VGPR spill — r4/r5).
// ---------------------------------------------------------------------------
__global__ __launch_bounds__(256) void k_mode(const uint8_t* __restrict__ qpad,
                                              uint8_t* __restrict__ xm){
  __shared__ uint8_t tile[14 * 528];
  int tid = threadIdx.x;
  int img = blockIdx.x >> 7;
  int h0  = (blockIdx.x & 127) << 2;
  {
    const uint4* g4 = (const uint4*)(qpad + img * (522 * 528) + h0 * 528);
    uint4* t4 = (uint4*)tile;
    t4[tid] = g4[tid];
    if (tid < 206) t4[tid + 256] = g4[tid + 256];
  }
  __syncthreads();
  int r4 = tid >> 6;
  int w0 = (tid & 63) << 3;
  const uint8_t* base = tile + r4 * 528 + w0;
  uint32_t c0 = 0, c1 = 0, c2 = 0, c3 = 0, c4 = 0;
#define HINC(q) { uint32_t inc_ = 1u << (((q) & 3u) << 3); uint32_t rr_ = (q) >> 2; \
    c0 += (rr_==0u)?inc_:0u; c1 += (rr_==1u)?inc_:0u; c2 += (rr_==2u)?inc_:0u; \
    c3 += (rr_==3u)?inc_:0u; c4 += (rr_==4u)?inc_:0u; }
#define HDEC(q) { uint32_t inc_ = 1u << (((q) & 3u) << 3); uint32_t rr_ = (q) >> 2; \
    c0 -= (rr_==0u)?inc_:0u; c1 -= (rr_==1u)?inc_:0u; c2 -= (rr_==2u)?inc_:0u; \
    c3 -= (rr_==3u)?inc_:0u; c4 -= (rr_==4u)?inc_:0u; }
  #pragma unroll 1
  for (int r = 0; r < 11; ++r){
    const uint8_t* row = base + r * 528;
    #pragma unroll
    for (int j = 0; j < 11; ++j){ uint32_t q = row[j]; HINC(q); }
  }
  uint64_t packed = 0;
  #pragma unroll 1
  for (int s = 0; s < 8; ++s){
#define KEY(reg, sh, l) (((((reg) >> (sh)) & 0xffu) << 5) | (16u - (uint32_t)(l)))
    uint32_t m0 = umax2(umax2(KEY(c0,0,0),  KEY(c0,8,1)),  umax2(KEY(c0,16,2),  KEY(c0,24,3)));
    uint32_t m1 = umax2(umax2(KEY(c1,0,4),  KEY(c1,8,5)),  umax2(KEY(c1,16,6),  KEY(c1,24,7)));
    uint32_t m2 = umax2(umax2(KEY(c2,0,8),  KEY(c2,8,9)),  umax2(KEY(c2,16,10), KEY(c2,24,11)));
    uint32_t m3 = umax2(umax2(KEY(c3,0,12), KEY(c3,8,13)), umax2(KEY(c3,16,14), KEY(c3,24,15)));
    uint32_t m  = umax2(umax2(umax2(m0, m1), umax2(m2, m3)), KEY(c4,0,16));
#undef KEY
    uint32_t lvl = 16u - (m & 31u);
    packed |= ((uint64_t)lvl) << (8 * s);
    if (s < 7){
      #pragma unroll
      for (int r = 0; r < 11; ++r){
        uint32_t qo = base[r * 528 + s];      HDEC(qo);
        uint32_t qn = base[r * 528 + s + 11]; HINC(qn);
      }
    }
  }
#undef HINC
#undef HDEC
  *(uint64_t*)(xm + img * HW + (h0 + r4) * 512 + w0) = packed;
}

// ---------------------------------------------------------------------------
// block reduction of per-thread su[16]/sq[16] -> partials[block][32]
// ---------------------------------------------------------------------------
__device__ __forceinline__ void reduce16(float* su, float* sq, float* __restrict__ partials){
  __shared__ float lsum[32];
  int tid = threadIdx.x;
  if (tid < 32) lsum[tid] = 0.0f;
  __syncthreads();
  #pragma unroll
  for (int o = 0; o < 16; ++o){
    float s = su[o], q = sq[o];
    #pragma unroll
    for (int off = 32; off >= 1; off >>= 1){
      s += __shfl_xor(s, off);
      q += __shfl_xor(q, off);
    }
    if ((tid & 63) == 0){ atomicAdd(&lsum[o], s); atomicAdd(&lsum[16 + o], q); }
  }
  __syncthreads();
  if (tid < 32) partials[blockIdx.x * 32 + tid] = lsum[tid];
}

// ---------------------------------------------------------------------------
// K1: stats of p1 = conv1x1(xm). 4 px/thread. grid 512 x 256.
// ---------------------------------------------------------------------------
__global__ __launch_bounds__(256) void k_stats1(const uint8_t* __restrict__ xm,
                                                const float* __restrict__ w1,
                                                const float* __restrict__ b1,
                                                float* __restrict__ partials){
  int t0 = (blockIdx.x * 256 + threadIdx.x) << 2;
  int b = t0 >> 18, hw = t0 & (HW - 1);
  uint32_t q0 = *(const uint32_t*)(xm + (b * 3 + 0) * HW + hw);
  uint32_t q1 = *(const uint32_t*)(xm + (b * 3 + 1) * HW + hw);
  uint32_t q2 = *(const uint32_t*)(xm + (b * 3 + 2) * HW + hw);
  float su[16], sq[16];
  #pragma unroll
  for (int o = 0; o < 16; ++o){ su[o] = 0.0f; sq[o] = 0.0f; }
  #pragma unroll
  for (int px = 0; px < 4; ++px){
    float x0 = (float)((q0 >> (8 * px)) & 0xffu) * 0.0625f;
    float x1 = (float)((q1 >> (8 * px)) & 0xffu) * 0.0625f;
    float x2 = (float)((q2 >> (8 * px)) & 0xffu) * 0.0625f;
    #pragma unroll
    for (int o = 0; o < 16; ++o){
      float v = b1[o] + w1[o*3]*x0 + w1[o*3+1]*x1 + w1[o*3+2]*x2;
      su[o] += v; sq[o] += v * v;
    }
  }
  reduce16(su, sq, partials);
}

// ---------------------------------------------------------------------------
// K2: recompute p1, bn1+lrelu, p2 = conv1x1, stats of p2. 4 px/thread.
// ---------------------------------------------------------------------------
__global__ __launch_bounds__(256) void k_stats2(const uint8_t* __restrict__ xm,
                                                const float* __restrict__ w1,
                                                const float* __restrict__ b1,
                                                const float* __restrict__ w2,
                                                const float* __restrict__ b2,
                                                const float* __restrict__ params,
                                                float* __restrict__ partials){
  int t0 = (blockIdx.x * 256 + threadIdx.x) << 2;
  int b = t0 >> 18, hw = t0 & (HW - 1);
  uint32_t q0 = *(const uint32_t*)(xm + (b * 3 + 0) * HW + hw);
  uint32_t q1 = *(const uint32_t*)(xm + (b * 3 + 1) * HW + hw);
  uint32_t q2 = *(const uint32_t*)(xm + (b * 3 + 2) * HW + hw);
  float tv[4][16];
  #pragma unroll
  for (int px = 0; px < 4; ++px){
    float x0 = (float)((q0 >> (8 * px)) & 0xffu) * 0.0625f;
    float x1 = (float)((q1 >> (8 * px)) & 0xffu) * 0.0625f;
    float x2 = (float)((q2 >> (8 * px)) & 0xffu) * 0.0625f;
    #pragma unroll
    for (int o = 0; o < 16; ++o){
      float v = b1[o] + w1[o*3]*x0 + w1[o*3+1]*x1 + w1[o*3+2]*x2;
      tv[px][o] = lrelu(v * params[o] + params[16 + o]);
    }
  }
  float su[16], sq[16];
  #pragma unroll
  for (int o = 0; o < 16; ++o){ su[o] = 0.0f; sq[o] = 0.0f; }
  #pragma unroll
  for (int o = 0; o < 16; ++o){
    #pragma unroll
    for (int px = 0; px < 4; ++px){
      float acc = b2[o];
      #pragma unroll
      for (int c = 0; c < 16; ++c) acc = fmaf(w2[o*16 + c], tv[px][c], acc);
      su[o] += acc; sq[o] += acc * acc;
    }
  }
  reduce16(su, sq, partials);
}

// ---------------------------------------------------------------------------
// K3: recompute p2, bn2+lrelu, write p (bf16). 4 px/thread.
// ---------------------------------------------------------------------------
__global__ __launch_bounds__(256) void k_prep(const uint8_t* __restrict__ xm,
                                              const float* __restrict__ w1,
                                              const float* __restrict__ b1,
                                              const float* __restrict__ w2,
                                              const float* __restrict__ b2,
                                              const float* __restrict__ params,
                                              bf16* __restrict__ p){
  int t0 = (blockIdx.x * 256 + threadIdx.x) << 2;
  int b = t0 >> 18, hw = t0 & (HW - 1);
  uint32_t q0 = *(const uint32_t*)(xm + (b * 3 + 0) * HW + hw);
  uint32_t q1 = *(const uint32_t*)(xm + (b * 3 + 1) * HW + hw);
  uint32_t q2 = *(const uint32_t*)(xm + (b * 3 + 2) * HW + hw);
  float tv[4][16];
  #pragma unroll
  for (int px = 0; px < 4; ++px){
    float x0 = (float)((q0 >> (8 * px)) & 0xffu) * 0.0625f;
    float x1 = (float)((q1 >> (8 * px)) & 0xffu) * 0.0625f;
    float x2 = (float)((q2 >> (8 * px)) & 0xffu) * 0.0625f;
    #pragma unroll
    for (int o = 0; o < 16; ++o){
      float v = b1[o] + w1[o*3]*x0 + w1[o*3+1]*x1 + w1[o*3+2]*x2;
      tv[px][o] = lrelu(v * params[o] + params[16 + o]);
    }
  }
  #pragma unroll
  for (int o = 0; o < 16; ++o){
    uint32_t w01 = 0, w23 = 0;
    #pragma unroll
    for (int px = 0; px < 4; ++px){
      float acc = b2[o];
      #pragma unroll
      for (int c = 0; c < 16; ++c) acc = fmaf(w2[o*16 + c], tv[px][c], acc);
      float v = lrelu(acc * params[32 + o] + params[48 + o]);
      uint32_t bits = (uint32_t)f2bu(v);
      if (px == 0) w01 = bits;
      else if (px == 1) w01 |= bits << 16;
      else if (px == 2) w23 = bits;
      else w23 |= bits << 16;
    }
    uint2 ov; ov.x = w01; ov.y = w23;
    *(uint2*)((ushort*)p + (b * 16 + o) * HW + hw) = ov;
  }
}

// ---------------------------------------------------------------------------
// row loader for depthwise conv: 10 values (cols w0-1 .. w0+8), zero-padded.
// ---------------------------------------------------------------------------
__device__ __forceinline__ void load_row10(const ushort* __restrict__ rp, int w0, float* v){
  uint4 cc = *(const uint4*)(rp + w0);
  uint32_t l = (w0 == 0)   ? 0u : (uint32_t)rp[w0 - 1];
  uint32_t r = (w0 == 504) ? 0u : (uint32_t)rp[w0 + 8];
  v[0] = us2f(l);
  v[1] = us2f(cc.x & 0xffffu); v[2] = us2f(cc.x >> 16);
  v[3] = us2f(cc.y & 0xffffu); v[4] = us2f(cc.y >> 16);
  v[5] = us2f(cc.z & 0xffffu); v[6] = us2f(cc.z >> 16);
  v[7] = us2f(cc.w & 0xffffu); v[8] = us2f(cc.w >> 16);
  v[9] = us2f(r);
}

__device__ __forceinline__ void zero_row10(float* v){
  #pragma unroll
  for (int j = 0; j < 10; ++j) v[j] = 0.0f;
}

__device__ __forceinline__ void reduce2(float s, float q, float* __restrict__ partials){
  __shared__ float l2[2];
  int tid = threadIdx.x;
  if (tid < 2) l2[tid] = 0.0f;
  __syncthreads();
  #pragma unroll
  for (int off = 32; off >= 1; off >>= 1){
    s += __shfl_xor(s, off);
    q += __shfl_xor(q, off);
  }
  if ((tid & 63) == 0){ atomicAdd(&l2[0], s); atomicAdd(&l2[1], q); }
  __syncthreads();
  if (tid < 2) partials[blockIdx.x * 2 + tid] = l2[tid];
}

// ---------------------------------------------------------------------------
// A: conv stats of p + write c0 = conv(p) (bf16). grid 4096.
// ---------------------------------------------------------------------------
__global__ __launch_bounds__(256) void k_convstat(const bf16* __restrict__ d,
                                                  const float* __restrict__ dw,
                                                  float* __restrict__ P1,
                                                  bf16* __restrict__ cout){
  int bid = blockIdx.x;
  int plane = bid >> 7, rg = bid & 127;
  int f = plane & 15;
  int tid = threadIdx.x;
  int h  = (rg << 2) + (tid >> 6);
  int w0 = (tid & 63) << 3;
  const ushort* pl = (const ushort*)d + plane * HW;
  float wf[9];
  #pragma unroll
  for (int i = 0; i < 9; ++i) wf[i] = dw[f * 9 + i];
  float v[3][10];
  #pragma unroll
  for (int dy = 0; dy < 3; ++dy){
    int row = h + dy - 1;
    if ((unsigned)row < 512u) load_row10(pl + row * 512, w0, v[dy]);
    else zero_row10(v[dy]);
  }
  float s = 0.0f, q = 0.0f;
  uint32_t cb[4];
  #pragma unroll
  for (int k = 0; k < 8; ++k){
    float acc = 0.0f;
    #pragma unroll
    for (int dy = 0; dy < 3; ++dy)
      #pragma unroll
      for (int dx = 0; dx < 3; ++dx)
        acc = fmaf(wf[dy*3 + dx], v[dy][k + dx], acc);
    s += acc; q += acc * acc;
    uint32_t bits = (uint32_t)f2bu(acc);
    if ((k & 1) == 0) cb[k >> 1] = bits; else cb[k >> 1] |= bits << 16;
  }
  uint4 cv; cv.x = cb[0]; cv.y = cb[1]; cv.z = cb[2]; cv.w = cb[3];
  *(uint4*)((ushort*)cout + plane * HW + h * 512 + w0) = cv;
  reduce2(s, q, P1);
}

// ---------------------------------------------------------------------------
// wave-parallel channel-f sum of a [32 planes][128 rg][2] partials buffer.
// ---------------------------------------------------------------------------
__device__ __forceinline__ void chan_sum_wave(const float* __restrict__ P, int f, int lane,
                                              double& S, double& Q){
  S = 0.0; Q = 0.0;
  #pragma unroll
  for (int i = 0; i < 4; ++i){
    int e = lane + i * 64;                    // 0..255
    int blk = (((e >> 7) * 16 + f) << 7) + (e & 127);
    S += (double)P[blk * 2];
    Q += (double)P[blk * 2 + 1];
  }
  #pragma unroll
  for (int off = 32; off >= 1; off >>= 1){
    S += __shfl_xor(S, off);
    Q += __shfl_xor(Q, off);
  }
}

// ---------------------------------------------------------------------------
// FUSED loop kernel (c-carry, NO d-store). grid 4096, 256 threads.
//   prologue: bnA params (sc,sh) for channel f from P1in (wave shuffle);
//             one block per channel also saves (sc,sh) -> dparams for k_final
//   main:     d = lrelu(cin*sc+sh) (1 uint4 load) -> LDS strip only; P2 stats
//   halo:     same for rows h0-1 / h0+4 (bit-identical recompute)
//   strip:    c_next = conv(d strip) -> cout (bf16) + P1out stats
// ---------------------------------------------------------------------------
__global__ __launch_bounds__(256) void k_bnfused(const bf16* __restrict__ cin,
                                                 const float* __restrict__ dw,
                                                 const float* __restrict__ gd,
                                                 const float* __restrict__ bd,
                                                 const float* __restrict__ P1in,
                                                 bf16* __restrict__ cout,
                                                 float* __restrict__ P2out,
                                                 float* __restrict__ P1out,
                                                 float* __restrict__ dparams,
                                                 int t, int write_c){
  __shared__ ushort strip[6][512];
  __shared__ float acc4[4];
  int bid = blockIdx.x;
  int plane = bid >> 7, rg = bid & 127;
  int f = plane & 15;
  int tid = threadIdx.x;

  double S, Q;
  chan_sum_wave(P1in, f, tid & 63, S, Q);
  float sc, sh;
  {
    double m = S / 524288.0;
    double v = Q / 524288.0 - m * m;
    sc = gd[f] / sqrtf((float)v + EPSF);
    sh = bd[f] - (float)m * sc;
  }
  // one block per channel saves (sc,sh) for k_final's d-recompute
  if (plane < 16 && rg == 0 && tid == 0){
    dparams[512 + t * 32 + 2 * f]     = sc;
    dparams[512 + t * 32 + 2 * f + 1] = sh;
  }
  if (tid < 4) acc4[tid] = 0.0f;

  int h0 = rg << 2;
  int h  = h0 + (tid >> 6);
  int w0 = (tid & 63) << 3;
  const ushort* cpl = (const ushort*)cin + plane * HW;

  // main rows: d = lrelu(c*sc+sh) -> strip (bf16) + stats; NO global d write
  float s2 = 0.0f, q2 = 0.0f;
  {
    uint4 cv = *(const uint4*)(cpl + h * 512 + w0);
    float cf[8];
    cf[0] = us2f(cv.x & 0xffffu); cf[1] = us2f(cv.x >> 16);
    cf[2] = us2f(cv.y & 0xffffu); cf[3] = us2f(cv.y >> 16);
    cf[4] = us2f(cv.z & 0xffffu); cf[5] = us2f(cv.z >> 16);
    cf[6] = us2f(cv.w & 0xffffu); cf[7] = us2f(cv.w >> 16);
    uint32_t ob[4];
    #pragma unroll
    for (int k = 0; k < 8; ++k){
      float vv = lrelu(fmaf(cf[k], sc, sh));
      uint32_t bits = (uint32_t)f2bu(vv);
      if ((k & 1) == 0) ob[k >> 1] = bits; else ob[k >> 1] |= bits << 16;
      s2 += vv; q2 += vv * vv;
    }
    uint4 ov; ov.x = ob[0]; ov.y = ob[1]; ov.z = ob[2]; ov.w = ob[3];
    *(uint4*)&strip[1 + (tid >> 6)][w0] = ov;
  }

  // halo rows (threads 0..63 -> row h0-1, 64..127 -> row h0+4)
  if (tid < 128){
    int hh = (tid < 64) ? (h0 - 1) : (h0 + 4);
    int si = (tid < 64) ? 0 : 5;
    int wh0 = (tid & 63) << 3;
    uint4 hv; hv.x = 0; hv.y = 0; hv.z = 0; hv.w = 0;
    if ((unsigned)hh < 512u){
      uint4 cv = *(const uint4*)(cpl + hh * 512 + wh0);
      float cf[8];
      cf[0] = us2f(cv.x & 0xffffu); cf[1] = us2f(cv.x >> 16);
      cf[2] = us2f(cv.y & 0xffffu); cf[3] = us2f(cv.y >> 16);
      cf[4] = us2f(cv.z & 0xffffu); cf[5] = us2f(cv.z >> 16);
      cf[6] = us2f(cv.w & 0xffffu); cf[7] = us2f(cv.w >> 16);
      uint32_t hb[4];
      #pragma unroll
      for (int k = 0; k < 8; ++k){
        float vv = lrelu(fmaf(cf[k], sc, sh));
        uint32_t bits = (uint32_t)f2bu(vv);
        if ((k & 1) == 0) hb[k >> 1] = bits; else hb[k >> 1] |= bits << 16;
      }
      hv.x = hb[0]; hv.y = hb[1]; hv.z = hb[2]; hv.w = hb[3];
    }
    *(uint4*)&strip[si][wh0] = hv;
  }
  __syncthreads();

  // strip conv: c_next = conv(d); stats + optional bf16 store
  float wf[9];
  #pragma unroll
  for (int i = 0; i < 9; ++i) wf[i] = dw[f * 9 + i];
  float s1 = 0.0f, q1 = 0.0f;
  {
    int si = 1 + (tid >> 6);
    float v[3][10];
    #pragma unroll
    for (int dy = 0; dy < 3; ++dy)
      load_row10(&strip[si - 1 + dy][0], w0, v[dy]);
    uint32_t cb[4];
    #pragma unroll
    for (int k = 0; k < 8; ++k){
      float acc = 0.0f;
      #pragma unroll
      for (int dy = 0; dy < 3; ++dy)
        #pragma unroll
        for (int dx = 0; dx < 3; ++dx)
          acc = fmaf(wf[dy*3 + dx], v[dy][k + dx], acc);
      s1 += acc; q1 += acc * acc;
      uint32_t bits = (uint32_t)f2bu(acc);
      if ((k & 1) == 0) cb[k >> 1] = bits; else cb[k >> 1] |= bits << 16;
    }
    if (write_c){
      uint4 cv2; cv2.x = cb[0]; cv2.y = cb[1]; cv2.z = cb[2]; cv2.w = cb[3];
      *(uint4*)((ushort*)cout + plane * HW + h * 512 + w0) = cv2;
    }
  }

  // epilogue: reduce (s2,q2,s1,q1) across block, write partials
  #pragma unroll
  for (int off = 32; off >= 1; off >>= 1){
    s2 += __shfl_xor(s2, off);
    q2 += __shfl_xor(q2, off);
    s1 += __shfl_xor(s1, off);
    q1 += __shfl_xor(q1, off);
  }
  if ((tid & 63) == 0){
    atomicAdd(&acc4[0], s2); atomicAdd(&acc4[1], q2);
    atomicAdd(&acc4[2], s1); atomicAdd(&acc4[3], q1);
  }
  __syncthreads();
  if (tid < 2)      P2out[bid * 2 + tid]       = acc4[tid];
  else if (tid < 4) P1out[bid * 2 + (tid - 2)] = acc4[tid];
}

// ---------------------------------------------------------------------------
// finalize: prepare-stage BN (512-block x 32 partials layout), grid 1
// ---------------------------------------------------------------------------
__global__ __launch_bounds__(256) void k_fin_prep(const float* __restrict__ partials,
                                                  const float* __restrict__ g,
                                                  const float* __restrict__ bb,
                                                  float* __restrict__ params,
                                                  int offS, int offT){
  int tid = threadIdx.x;
  int o = tid & 15, c = tid >> 4;
  double S = 0.0, Q = 0.0;
  for (int i = c * 32; i < (c + 1) * 32; ++i){
    S += (double)partials[i * 32 + o];
    Q += (double)partials[i * 32 + 16 + o];
  }
  __shared__ double lS[256], lQ[256];
  lS[tid] = S; lQ[tid] = Q; __syncthreads();
  for (int st = 8; st >= 1; st >>= 1){
    if (c < st){ lS[tid] += lS[tid + st * 16]; lQ[tid] += lQ[tid + st * 16]; }
    __syncthreads();
  }
  if (tid < 16){
    double m = lS[tid] / 524288.0;
    double v = lQ[tid] / 524288.0 - m * m;
    float sc = g[tid] / sqrtf((float)v + EPSF);
    params[offS + tid] = sc;
    params[offT + tid] = bb[tid] - (float)m * sc;
  }
}

// ---------------------------------------------------------------------------
// k_fin_all: 80 wdt/hgt param quadruples, one (t,f) pair per wave. grid 20.
// ---------------------------------------------------------------------------
__global__ __launch_bounds__(256) void k_fin_all(const float* __restrict__ P2,
                                                 const float* __restrict__ ww,
                                                 const float* __restrict__ gw,
                                                 const float* __restrict__ bw,
                                                 const float* __restrict__ wh,
                                                 const float* __restrict__ gh,
                                                 const float* __restrict__ bh,
                                                 float* __restrict__ dparams){
  int tid = threadIdx.x;
  int wid = tid >> 6, lane = tid & 63;
  int pair = blockIdx.x * 4 + wid;              // 0..79
  int t = pair >> 4, f = pair & 15;
  double S, Q;
  chan_sum_wave(P2 + t * 8192, f, lane, S, Q);
  if (lane == 0){
    float m = (float)(S / 524288.0);
    float v = (float)(Q / 524288.0) - m * m;
    float sw = ww[f] * gw[f] / sqrtf(ww[f] * ww[f] * v + EPSF);
    float tw = bw[f] - m * sw;
    float s2 = wh[f] * gh[f] / sqrtf(wh[f] * wh[f] * v + EPSF);
    float t2 = bh[f] - m * s2;
    dparams[t * 64 + f]      = sw;
    dparams[t * 64 + 16 + f] = tw;
    dparams[t * 64 + 32 + f] = s2;
    dparams[t * 64 + 48 + f] = t2;
  }
}

// ---------------------------------------------------------------------------
// F: assemble out. 8 px/thread; all 12 uint4 loads up-front; d_t recomputed
// on the fly from c_t and the saved (sc_t, sh_t).
// ---------------------------------------------------------------------------
__device__ __forceinline__ void conv8(uint4 cc, float* v){
  v[0] = us2f(cc.x & 0xffffu); v[1] = us2f(cc.x >> 16);
  v[2] = us2f(cc.y & 0xffffu); v[3] = us2f(cc.y >> 16);
  v[4] = us2f(cc.z & 0xffffu); v[5] = us2f(cc.z >> 16);
  v[6] = us2f(cc.w & 0xffffu); v[7] = us2f(cc.w >> 16);
}

__global__ __launch_bounds__(256) void k_final(const bf16* __restrict__ p,
                                               const bf16* __restrict__ c1,
                                               const bf16* __restrict__ c2,
                                               const bf16* __restrict__ c3,
                                               const bf16* __restrict__ c4,
                                               const bf16* __restrict__ c5,
                                               const float* __restrict__ dparams,
                                               float* __restrict__ out){
  int tid = threadIdx.x;
  int f = blockIdx.x >> 7;                      // 128 blocks per f
  int gid = blockIdx.x * 256 + tid;             // 0 .. 524287
  int hw = (gid & 32767) << 3;
  int fo = f * HW + hw;
  int f1 = (16 + f) * HW + hw;

  uint4 rp0 = *(const uint4*)((const ushort*)p + fo);
  uint4 rp1 = *(const uint4*)((const ushort*)p + f1);
  uint4 r0a = *(const uint4*)((const ushort*)c1 + fo);
  uint4 r0b = *(const uint4*)((const ushort*)c1 + f1);
  uint4 r1a = *(const uint4*)((const ushort*)c2 + fo);
  uint4 r1b = *(const uint4*)((const ushort*)c2 + f1);
  uint4 r2a = *(const uint4*)((const ushort*)c3 + fo);
  uint4 r2b = *(const uint4*)((const ushort*)c3 + f1);
  uint4 r3a = *(const uint4*)((const ushort*)c4 + fo);
  uint4 r3b = *(const uint4*)((const ushort*)c4 + f1);
  uint4 r4a = *(const uint4*)((const ushort*)c5 + fo);
  uint4 r4b = *(const uint4*)((const ushort*)c5 + f1);

  float swA[5], twA[5], shA[5], thA[5], scA[5], sbA[5];
  #pragma unroll
  for (int t = 0; t < 5; ++t){
    swA[t] = dparams[t * 64 + f];
    twA[t] = dparams[t * 64 + 16 + f];
    shA[t] = dparams[t * 64 + 32 + f];
    thA[t] = dparams[t * 64 + 48 + f];
    scA[t] = dparams[512 + t * 32 + 2 * f];
    sbA[t] = dparams[512 + t * 32 + 2 * f + 1];
  }

  float pf[8], pg[8];
  conv8(rp0, pf); conv8(rp1, pg);
  float a00[8], a01[8], a10[8], a11[8];
  #pragma unroll
  for (int k = 0; k < 8; ++k){ a00[k] = pf[k]; a01[k] = pg[k]; a10[k] = pf[k]; a11[k] = pg[k]; }

  uint4 ra[5] = { r0a, r1a, r2a, r3a, r4a };
  uint4 rb[5] = { r0b, r1b, r2b, r3b, r4b };
  #pragma unroll
  for (int t = 0; t < 5; ++t){
    float cv0[8], cv1[8];
    conv8(ra[t], cv0); conv8(rb[t], cv1);
    float sw = swA[t], tw = twA[t], sh = shA[t], th = thA[t];
    float sc = scA[t], sb = sbA[t];
    #pragma unroll
    for (int k = 0; k < 8; ++k){
      float dv0 = lrelu(fmaf(cv0[k], sc, sb));
      float dv1 = lrelu(fmaf(cv1[k], sc, sb));
      a00[k] += lrelu(fmaf(dv0, sw, tw));
      a01[k] += lrelu(fmaf(dv0, sh, th));
      a10[k] += lrelu(fmaf(dv1, sw, tw));
      a11[k] += lrelu(fmaf(dv1, sh, th));
    }
  }
  #pragma unroll
  for (int half = 0; half < 2; ++half){
    float4 v0 = { a00[half*4+0], a00[half*4+1], a00[half*4+2], a00[half*4+3] };
    float4 v1 = { a01[half*4+0], a01[half*4+1], a01[half*4+2], a01[half*4+3] };
    float4 v2 = { a10[half*4+0], a10[half*4+1], a10[half*4+2], a10[half*4+3] };
    float4 v3 = { a11[half*4+0], a11[half*4+1], a11[half*4+2], a11[half*4+3] };
    *(float4*)(out + f * HW + hw + half*4)        = v0;
    *(float4*)(out + (16 + f) * HW + hw + half*4) = v1;
    *(float4*)(out + (32 + f) * HW + hw + half*4) = v2;
    *(float4*)(out + (48 + f) * HW + hw + half*4) = v3;
  }
}

// ---------------------------------------------------------------------------
extern "C" void kernel_launch(void* const* d_in, const int* in_sizes, int n_in,
                              void* d_out, int out_size, void* d_ws, size_t ws_size,
                              hipStream_t stream){
  (void)in_sizes; (void)n_in; (void)out_size;
  const float* x   = (const float*)d_in[0];
  const float* w1  = (const float*)d_in[1];
  const float* b1  = (const float*)d_in[2];
  const float* g1  = (const float*)d_in[3];
  const float* be1 = (const float*)d_in[4];
  const float* w2  = (const float*)d_in[5];
  const float* b2  = (const float*)d_in[6];
  const float* g2  = (const float*)d_in[7];
  const float* be2 = (const float*)d_in[8];
  const float* dw  = (const float*)d_in[9];
  const float* gd  = (const float*)d_in[10];
  const float* bd  = (const float*)d_in[11];
  const float* ww  = (const float*)d_in[12];
  const float* gw  = (const float*)d_in[13];
  const float* bw  = (const float*)d_in[14];
  const float* wh  = (const float*)d_in[15];
  const float* gh  = (const float*)d_in[16];
  const float* bh  = (const float*)d_in[17];
  float* out = (float*)d_out;

  char* ws = (char*)d_ws;
  size_t off = 0;
  auto alloc = [&](size_t sz) -> void* {
    void* ptr = ws + off;
    off = (off + sz + 4095) & ~(size_t)4095;
    return ptr;
  };
  uint8_t* qpad  = (uint8_t*)alloc((size_t)6 * 522 * 528);
  uint8_t* xm    = (uint8_t*)alloc((size_t)6 * HW);
  bf16*    p     = (bf16*)   alloc((size_t)32 * HW * 2);
  bf16*    cbuf[5];
  for (int i = 0; i < 5; ++i) cbuf[i] = (bf16*)alloc((size_t)32 * HW * 2);
  float*   Pp     = (float*)  alloc((size_t)512 * 32 * 4);
  float*   P1a    = (float*)  alloc((size_t)4096 * 2 * 4);
  float*   P1b    = (float*)  alloc((size_t)4096 * 2 * 4);
  float*   P2     = (float*)  alloc((size_t)5 * 4096 * 2 * 4);
  float*   params = (float*)  alloc(4096);
  float*   dparams= (float*)  alloc(4096);
  if (ws_size < off) return;   // workspace too small: fail visibly (untouched out)

  k_quant_pad<<<dim3((6*522*522 + 255)/256), dim3(256), 0, stream>>>(x, qpad);
  k_mode     <<<dim3(768), dim3(256), 0, stream>>>(qpad, xm);
  k_stats1   <<<dim3(512), dim3(256), 0, stream>>>(xm, w1, b1, Pp);
  k_fin_prep <<<dim3(1),   dim3(256), 0, stream>>>(Pp, g1, be1, params, 0, 16);
  k_stats2   <<<dim3(512), dim3(256), 0, stream>>>(xm, w1, b1, w2, b2, params, Pp);
  k_fin_prep <<<dim3(1),   dim3(256), 0, stream>>>(Pp, g2, be2, params, 32, 48);
  k_prep     <<<dim3(512), dim3(256), 0, stream>>>(xm, w1, b1, w2, b2, params, p);
  k_convstat <<<dim3(4096), dim3(256), 0, stream>>>(p, dw, P1a, cbuf[0]);

  float* Pin = P1a; float* Pout = P1b;
  for (int t = 0; t < 5; ++t){
    k_bnfused<<<dim3(4096), dim3(256), 0, stream>>>(
        cbuf[t], dw, gd, bd, Pin,
        (t < 4) ? cbuf[t + 1] : cbuf[0],      // dummy target when !write_c
        P2 + t * 8192, Pout, dparams, t, (t < 4) ? 1 : 0);
    float* tmp = Pin; Pin = Pout; Pout = tmp;
  }
  k_fin_all<<<dim3(20), dim3(256), 0, stream>>>(P2, ww, gw, bw, wh, gh, bh, dparams);
  k_final<<<dim3(2048), dim3(256), 0, stream>>>(p, cbuf[0], cbuf[1], cbuf[2],
                                                cbuf[3], cbuf[4], dparams, out);
}

// Round 13
// 210.329 us; speedup vs baseline: 3.8626x; 1.0625x over previous
//
#include <hip/hip_runtime.h>
#include <hip/hip_bf16.h>
#include <stdint.h>
#include <stddef.h>

#define HW 262144          // 512*512
#define EPSF 1e-5f

typedef __hip_bfloat16 bf16;

__device__ __forceinline__ float us2f(uint32_t u){
  union { uint32_t i; float f; } c; c.i = u << 16; return c.f;
}
__device__ __forceinline__ ushort f2bu(float v){
  union { bf16 h; ushort u; } c; c.h = __float2bfloat16(v); return c.u;
}
__device__ __forceinline__ float lrelu(float v){ return v > 0.0f ? v : 0.01f * v; }
__device__ __forceinline__ uint32_t umax2(uint32_t a, uint32_t b){ return a > b ? a : b; }

// ---------------------------------------------------------------------------
// K0: 11x11 mode filter with FUSED quantize+reflect-pad staging.
// Each block stages its 14x522 u8 tile straight from x (reflect indexing,
// k = rint(x*255/16)); per-thread sliding 17-bin histogram packed 8-bit in 5
// u32 regs (rolled loops to avoid the r3/r4 VGPR spill). Grid 768 x 256.
// ---------------------------------------------------------------------------
__global__ __launch_bounds__(256) void k_mode(const float* __restrict__ x,
                                              uint8_t* __restrict__ xm){
  __shared__ uint8_t tile[14 * 528];
  int tid = threadIdx.x;
  int img = blockIdx.x >> 7;
  int h0  = (blockIdx.x & 127) << 2;          // first output row of block
  {
    const float* xp = x + img * HW;
    #pragma unroll 1
    for (int r = 0; r < 14; ++r){
      int hs = h0 + r - 5; hs = hs < 0 ? -hs : hs; if (hs > 511) hs = 1022 - hs;
      const float* row = xp + hs * 512;
      for (int c = tid; c < 522; c += 256){
        int ws = c - 5; ws = ws < 0 ? -ws : ws; if (ws > 511) ws = 1022 - ws;
        float v = row[ws];
        int k = (int)rintf((v * 255.0f) / 16.0f);   // same expr as reference
        tile[r * 528 + c] = (uint8_t)k;
      }
    }
  }
  __syncthreads();
  int r4 = tid >> 6;                          // row within block 0..3
  int w0 = (tid & 63) << 3;                   // 0..504 (max col touched: 521)
  const uint8_t* base = tile + r4 * 528 + w0;
  uint32_t c0 = 0, c1 = 0, c2 = 0, c3 = 0, c4 = 0;
#define HINC(q) { uint32_t inc_ = 1u << (((q) & 3u) << 3); uint32_t rr_ = (q) >> 2; \
    c0 += (rr_==0u)?inc_:0u; c1 += (rr_==1u)?inc_:0u; c2 += (rr_==2u)?inc_:0u; \
    c3 += (rr_==3u)?inc_:0u; c4 += (rr_==4u)?inc_:0u; }
#define HDEC(q) { uint32_t inc_ = 1u << (((q) & 3u) << 3); uint32_t rr_ = (q) >> 2; \
    c0 -= (rr_==0u)?inc_:0u; c1 -= (rr_==1u)?inc_:0u; c2 -= (rr_==2u)?inc_:0u; \
    c3 -= (rr_==3u)?inc_:0u; c4 -= (rr_==4u)?inc_:0u; }
  #pragma unroll 1
  for (int r = 0; r < 11; ++r){
    const uint8_t* row = base + r * 528;
    #pragma unroll
    for (int j = 0; j < 11; ++j){ uint32_t q = row[j]; HINC(q); }
  }
  uint64_t packed = 0;
  #pragma unroll 1
  for (int s = 0; s < 8; ++s){
    // key(l) = (cnt<<5) | (16-l); max key -> max cnt, tie -> smallest level
#define KEY(reg, sh, l) (((((reg) >> (sh)) & 0xffu) << 5) | (16u - (uint32_t)(l)))
    uint32_t m0 = umax2(umax2(KEY(c0,0,0),  KEY(c0,8,1)),  umax2(KEY(c0,16,2),  KEY(c0,24,3)));
    uint32_t m1 = umax2(umax2(KEY(c1,0,4),  KEY(c1,8,5)),  umax2(KEY(c1,16,6),  KEY(c1,24,7)));
    uint32_t m2 = umax2(umax2(KEY(c2,0,8),  KEY(c2,8,9)),  umax2(KEY(c2,16,10), KEY(c2,24,11)));
    uint32_t m3 = umax2(umax2(KEY(c3,0,12), KEY(c3,8,13)), umax2(KEY(c3,16,14), KEY(c3,24,15)));
    uint32_t m  = umax2(umax2(umax2(m0, m1), umax2(m2, m3)), KEY(c4,0,16));
#undef KEY
    uint32_t lvl = 16u - (m & 31u);
    packed |= ((uint64_t)lvl) << (8 * s);
    if (s < 7){
      #pragma unroll
      for (int r = 0; r < 11; ++r){
        uint32_t qo = base[r * 528 + s];      HDEC(qo);
        uint32_t qn = base[r * 528 + s + 11]; HINC(qn);
      }
    }
  }
#undef HINC
#undef HDEC
  *(uint64_t*)(xm + img * HW + (h0 + r4) * 512 + w0) = packed;
}

// ---------------------------------------------------------------------------
// block reduction of per-thread su[16]/sq[16] -> partials[block][32]
// ---------------------------------------------------------------------------
__device__ __forceinline__ void reduce16(float* su, float* sq, float* __restrict__ partials){
  __shared__ float lsum[32];
  int tid = threadIdx.x;
  if (tid < 32) lsum[tid] = 0.0f;
  __syncthreads();
  #pragma unroll
  for (int o = 0; o < 16; ++o){
    float s = su[o], q = sq[o];
    #pragma unroll
    for (int off = 32; off >= 1; off >>= 1){
      s += __shfl_xor(s, off);
      q += __shfl_xor(q, off);
    }
    if ((tid & 63) == 0){ atomicAdd(&lsum[o], s); atomicAdd(&lsum[16 + o], q); }
  }
  __syncthreads();
  if (tid < 32) partials[blockIdx.x * 32 + tid] = lsum[tid];
}

// ---------------------------------------------------------------------------
// per-block BN-param computation from a [512][32] partials buffer.
// FULLY UNROLLED 4-accumulator load sweep (the r8 regression was a
// `#pragma unroll 1` serial chain); fixed combine order -> bit-identical
// (sc,sh) in every block. ~64KB/block from L2.
// ---------------------------------------------------------------------------
__device__ __forceinline__ void prep_params(const float* __restrict__ Pp,
                                            const float* __restrict__ g,
                                            const float* __restrict__ bb,
                                            float* prm, float* partS, double* totS){
  int tid = threadIdx.x;
  int o = tid & 31, gg = tid >> 5;            // 8 groups x 32 outputs
  float s0 = 0.0f, s1 = 0.0f, s2 = 0.0f, s3 = 0.0f;
  #pragma unroll
  for (int j = 0; j < 64; j += 4){
    s0 += Pp[(gg * 64 + j    ) * 32 + o];
    s1 += Pp[(gg * 64 + j + 1) * 32 + o];
    s2 += Pp[(gg * 64 + j + 2) * 32 + o];
    s3 += Pp[(gg * 64 + j + 3) * 32 + o];
  }
  partS[gg * 32 + o] = (s0 + s1) + (s2 + s3);
  __syncthreads();
  if (tid < 32){
    double t = 0.0;
    #pragma unroll
    for (int k = 0; k < 8; ++k) t += (double)partS[k * 32 + tid];
    totS[tid] = t;
  }
  __syncthreads();
  if (tid < 16){
    double m = totS[tid] / 524288.0;
    double v = totS[16 + tid] / 524288.0 - m * m;
    float sc = g[tid] / sqrtf((float)v + EPSF);
    prm[tid] = sc;
    prm[16 + tid] = bb[tid] - (float)m * sc;
  }
  __syncthreads();
}

// ---------------------------------------------------------------------------
// K1: stats of p1 = conv1x1(xm). 4 px/thread. grid 512 x 256. -> Pp1
// ---------------------------------------------------------------------------
__global__ __launch_bounds__(256) void k_stats1(const uint8_t* __restrict__ xm,
                                                const float* __restrict__ w1,
                                                const float* __restrict__ b1,
                                                float* __restrict__ partials){
  int t0 = (blockIdx.x * 256 + threadIdx.x) << 2;
  int b = t0 >> 18, hw = t0 & (HW - 1);
  uint32_t q0 = *(const uint32_t*)(xm + (b * 3 + 0) * HW + hw);
  uint32_t q1 = *(const uint32_t*)(xm + (b * 3 + 1) * HW + hw);
  uint32_t q2 = *(const uint32_t*)(xm + (b * 3 + 2) * HW + hw);
  float su[16], sq[16];
  #pragma unroll
  for (int o = 0; o < 16; ++o){ su[o] = 0.0f; sq[o] = 0.0f; }
  #pragma unroll
  for (int px = 0; px < 4; ++px){
    float x0 = (float)((q0 >> (8 * px)) & 0xffu) * 0.0625f;
    float x1 = (float)((q1 >> (8 * px)) & 0xffu) * 0.0625f;
    float x2 = (float)((q2 >> (8 * px)) & 0xffu) * 0.0625f;
    #pragma unroll
    for (int o = 0; o < 16; ++o){
      float v = b1[o] + w1[o*3]*x0 + w1[o*3+1]*x1 + w1[o*3+2]*x2;
      su[o] += v; sq[o] += v * v;
    }
  }
  reduce16(su, sq, partials);
}

// ---------------------------------------------------------------------------
// K2: prologue computes bn1 params from Pp1 (parallel loads); recompute p1,
// bn1+lrelu, p2 = conv1x1, stats -> Pp2 (separate buffer, no race).
// ---------------------------------------------------------------------------
__global__ __launch_bounds__(256) void k_stats2(const uint8_t* __restrict__ xm,
                                                const float* __restrict__ w1,
                                                const float* __restrict__ b1,
                                                const float* __restrict__ w2,
                                                const float* __restrict__ b2,
                                                const float* __restrict__ Pp1,
                                                const float* __restrict__ g1,
                                                const float* __restrict__ be1,
                                                float* __restrict__ Pp2){
  __shared__ float prm[32];
  __shared__ float partS[8 * 32];
  __shared__ double totS[32];
  prep_params(Pp1, g1, be1, prm, partS, totS);
  int t0 = (blockIdx.x * 256 + threadIdx.x) << 2;
  int b = t0 >> 18, hw = t0 & (HW - 1);
  uint32_t q0 = *(const uint32_t*)(xm + (b * 3 + 0) * HW + hw);
  uint32_t q1 = *(const uint32_t*)(xm + (b * 3 + 1) * HW + hw);
  uint32_t q2 = *(const uint32_t*)(xm + (b * 3 + 2) * HW + hw);
  float tv[4][16];
  #pragma unroll
  for (int px = 0; px < 4; ++px){
    float x0 = (float)((q0 >> (8 * px)) & 0xffu) * 0.0625f;
    float x1 = (float)((q1 >> (8 * px)) & 0xffu) * 0.0625f;
    float x2 = (float)((q2 >> (8 * px)) & 0xffu) * 0.0625f;
    #pragma unroll
    for (int o = 0; o < 16; ++o){
      float v = b1[o] + w1[o*3]*x0 + w1[o*3+1]*x1 + w1[o*3+2]*x2;
      tv[px][o] = lrelu(v * prm[o] + prm[16 + o]);
    }
  }
  float su[16], sq[16];
  #pragma unroll
  for (int o = 0; o < 16; ++o){ su[o] = 0.0f; sq[o] = 0.0f; }
  #pragma unroll
  for (int o = 0; o < 16; ++o){
    #pragma unroll
    for (int px = 0; px < 4; ++px){
      float acc = b2[o];
      #pragma unroll
      for (int c = 0; c < 16; ++c) acc = fmaf(w2[o*16 + c], tv[px][c], acc);
      su[o] += acc; sq[o] += acc * acc;
    }
  }
  reduce16(su, sq, Pp2);
}

// ---------------------------------------------------------------------------
// K3: prologue computes bn1 (Pp1) + bn2 (Pp2) params; recompute p2,
// bn2+lrelu, write p (bf16). 4 px/thread.
// ---------------------------------------------------------------------------
__global__ __launch_bounds__(256) void k_prep(const uint8_t* __restrict__ xm,
                                              const float* __restrict__ w1,
                                              const float* __restrict__ b1,
                                              const float* __restrict__ w2,
                                              const float* __restrict__ b2,
                                              const float* __restrict__ Pp1,
                                              const float* __restrict__ g1,
                                              const float* __restrict__ be1,
                                              const float* __restrict__ Pp2,
                                              const float* __restrict__ g2,
                                              const float* __restrict__ be2,
                                              bf16* __restrict__ p){
  __shared__ float prm1[32], prm2[32];
  __shared__ float partS[8 * 32];
  __shared__ double totS[32];
  prep_params(Pp1, g1, be1, prm1, partS, totS);
  prep_params(Pp2, g2, be2, prm2, partS, totS);
  int t0 = (blockIdx.x * 256 + threadIdx.x) << 2;
  int b = t0 >> 18, hw = t0 & (HW - 1);
  uint32_t q0 = *(const uint32_t*)(xm + (b * 3 + 0) * HW + hw);
  uint32_t q1 = *(const uint32_t*)(xm + (b * 3 + 1) * HW + hw);
  uint32_t q2 = *(const uint32_t*)(xm + (b * 3 + 2) * HW + hw);
  float tv[4][16];
  #pragma unroll
  for (int px = 0; px < 4; ++px){
    float x0 = (float)((q0 >> (8 * px)) & 0xffu) * 0.0625f;
    float x1 = (float)((q1 >> (8 * px)) & 0xffu) * 0.0625f;
    float x2 = (float)((q2 >> (8 * px)) & 0xffu) * 0.0625f;
    #pragma unroll
    for (int o = 0; o < 16; ++o){
      float v = b1[o] + w1[o*3]*x0 + w1[o*3+1]*x1 + w1[o*3+2]*x2;
      tv[px][o] = lrelu(v * prm1[o] + prm1[16 + o]);
    }
  }
  #pragma unroll
  for (int o = 0; o < 16; ++o){
    uint32_t w01 = 0, w23 = 0;
    #pragma unroll
    for (int px = 0; px < 4; ++px){
      float acc = b2[o];
      #pragma unroll
      for (int c = 0; c < 16; ++c) acc = fmaf(w2[o*16 + c], tv[px][c], acc);
      float v = lrelu(acc * prm2[o] + prm2[16 + o]);
      uint32_t bits = (uint32_t)f2bu(v);
      if (px == 0) w01 = bits;
      else if (px == 1) w01 |= bits << 16;
      else if (px == 2) w23 = bits;
      else w23 |= bits << 16;
    }
    uint2 ov; ov.x = w01; ov.y = w23;
    *(uint2*)((ushort*)p + (b * 16 + o) * HW + hw) = ov;
  }
}

// ---------------------------------------------------------------------------
// row loader for depthwise conv: 10 values (cols w0-1 .. w0+8), zero-padded.
// ---------------------------------------------------------------------------
__device__ __forceinline__ void load_row10(const ushort* __restrict__ rp, int w0, float* v){
  uint4 cc = *(const uint4*)(rp + w0);
  uint32_t l = (w0 == 0)   ? 0u : (uint32_t)rp[w0 - 1];
  uint32_t r = (w0 == 504) ? 0u : (uint32_t)rp[w0 + 8];
  v[0] = us2f(l);
  v[1] = us2f(cc.x & 0xffffu); v[2] = us2f(cc.x >> 16);
  v[3] = us2f(cc.y & 0xffffu); v[4] = us2f(cc.y >> 16);
  v[5] = us2f(cc.z & 0xffffu); v[6] = us2f(cc.z >> 16);
  v[7] = us2f(cc.w & 0xffffu); v[8] = us2f(cc.w >> 16);
  v[9] = us2f(r);
}

__device__ __forceinline__ void zero_row10(float* v){
  #pragma unroll
  for (int j = 0; j < 10; ++j) v[j] = 0.0f;
}

__device__ __forceinline__ void reduce2(float s, float q, float* __restrict__ partials){
  __shared__ float l2[2];
  int tid = threadIdx.x;
  if (tid < 2) l2[tid] = 0.0f;
  __syncthreads();
  #pragma unroll
  for (int off = 32; off >= 1; off >>= 1){
    s += __shfl_xor(s, off);
    q += __shfl_xor(q, off);
  }
  if ((tid & 63) == 0){ atomicAdd(&l2[0], s); atomicAdd(&l2[1], q); }
  __syncthreads();
  if (tid < 2) partials[blockIdx.x * 2 + tid] = l2[tid];
}

// ---------------------------------------------------------------------------
// A: conv stats of p + write c0 = conv(p) (bf16). grid 4096.
// ---------------------------------------------------------------------------
__global__ __launch_bounds__(256) void k_convstat(const bf16* __restrict__ d,
                                                  const float* __restrict__ dw,
                                                  float* __restrict__ P1,
                                                  bf16* __restrict__ cout){
  int bid = blockIdx.x;
  int plane = bid >> 7, rg = bid & 127;
  int f = plane & 15;
  int tid = threadIdx.x;
  int h  = (rg << 2) + (tid >> 6);
  int w0 = (tid & 63) << 3;
  const ushort* pl = (const ushort*)d + plane * HW;
  float wf[9];
  #pragma unroll
  for (int i = 0; i < 9; ++i) wf[i] = dw[f * 9 + i];
  float v[3][10];
  #pragma unroll
  for (int dy = 0; dy < 3; ++dy){
    int row = h + dy - 1;
    if ((unsigned)row < 512u) load_row10(pl + row * 512, w0, v[dy]);
    else zero_row10(v[dy]);
  }
  float s = 0.0f, q = 0.0f;
  uint32_t cb[4];
  #pragma unroll
  for (int k = 0; k < 8; ++k){
    float acc = 0.0f;
    #pragma unroll
    for (int dy = 0; dy < 3; ++dy)
      #pragma unroll
      for (int dx = 0; dx < 3; ++dx)
        acc = fmaf(wf[dy*3 + dx], v[dy][k + dx], acc);
    s += acc; q += acc * acc;
    uint32_t bits = (uint32_t)f2bu(acc);
    if ((k & 1) == 0) cb[k >> 1] = bits; else cb[k >> 1] |= bits << 16;
  }
  uint4 cv; cv.x = cb[0]; cv.y = cb[1]; cv.z = cb[2]; cv.w = cb[3];
  *(uint4*)((ushort*)cout + plane * HW + h * 512 + w0) = cv;
  reduce2(s, q, P1);
}

// ---------------------------------------------------------------------------
// wave-parallel channel-f sum of a [32 planes][128 rg][2] partials buffer.
// ---------------------------------------------------------------------------
__device__ __forceinline__ void chan_sum_wave(const float* __restrict__ P, int f, int lane,
                                              double& S, double& Q){
  S = 0.0; Q = 0.0;
  #pragma unroll
  for (int i = 0; i < 4; ++i){
    int e = lane + i * 64;                    // 0..255
    int blk = (((e >> 7) * 16 + f) << 7) + (e & 127);
    S += (double)P[blk * 2];
    Q += (double)P[blk * 2 + 1];
  }
  #pragma unroll
  for (int off = 32; off >= 1; off >>= 1){
    S += __shfl_xor(S, off);
    Q += __shfl_xor(Q, off);
  }
}

// ---------------------------------------------------------------------------
// FUSED loop kernel (c-carry, NO d-store). grid 4096, 256 threads.
// ---------------------------------------------------------------------------
__global__ __launch_bounds__(256) void k_bnfused(const bf16* __restrict__ cin,
                                                 const float* __restrict__ dw,
                                                 const float* __restrict__ gd,
                                                 const float* __restrict__ bd,
                                                 const float* __restrict__ P1in,
                                                 bf16* __restrict__ cout,
                                                 float* __restrict__ P2out,
                                                 float* __restrict__ P1out,
                                                 float* __restrict__ dparams,
                                                 int t, int write_c){
  __shared__ ushort strip[6][512];
  __shared__ float acc4[4];
  int bid = blockIdx.x;
  int plane = bid >> 7, rg = bid & 127;
  int f = plane & 15;
  int tid = threadIdx.x;

  double S, Q;
  chan_sum_wave(P1in, f, tid & 63, S, Q);
  float sc, sh;
  {
    double m = S / 524288.0;
    double v = Q / 524288.0 - m * m;
    sc = gd[f] / sqrtf((float)v + EPSF);
    sh = bd[f] - (float)m * sc;
  }
  if (plane < 16 && rg == 0 && tid == 0){
    dparams[512 + t * 32 + 2 * f]     = sc;
    dparams[512 + t * 32 + 2 * f + 1] = sh;
  }
  if (tid < 4) acc4[tid] = 0.0f;

  int h0 = rg << 2;
  int h  = h0 + (tid >> 6);
  int w0 = (tid & 63) << 3;
  const ushort* cpl = (const ushort*)cin + plane * HW;

  float s2 = 0.0f, q2 = 0.0f;
  {
    uint4 cv = *(const uint4*)(cpl + h * 512 + w0);
    float cf[8];
    cf[0] = us2f(cv.x & 0xffffu); cf[1] = us2f(cv.x >> 16);
    cf[2] = us2f(cv.y & 0xffffu); cf[3] = us2f(cv.y >> 16);
    cf[4] = us2f(cv.z & 0xffffu); cf[5] = us2f(cv.z >> 16);
    cf[6] = us2f(cv.w & 0xffffu); cf[7] = us2f(cv.w >> 16);
    uint32_t ob[4];
    #pragma unroll
    for (int k = 0; k < 8; ++k){
      float vv = lrelu(fmaf(cf[k], sc, sh));
      uint32_t bits = (uint32_t)f2bu(vv);
      if ((k & 1) == 0) ob[k >> 1] = bits; else ob[k >> 1] |= bits << 16;
      s2 += vv; q2 += vv * vv;
    }
    uint4 ov; ov.x = ob[0]; ov.y = ob[1]; ov.z = ob[2]; ov.w = ob[3];
    *(uint4*)&strip[1 + (tid >> 6)][w0] = ov;
  }

  if (tid < 128){
    int hh = (tid < 64) ? (h0 - 1) : (h0 + 4);
    int si = (tid < 64) ? 0 : 5;
    int wh0 = (tid & 63) << 3;
    uint4 hv; hv.x = 0; hv.y = 0; hv.z = 0; hv.w = 0;
    if ((unsigned)hh < 512u){
      uint4 cv = *(const uint4*)(cpl + hh * 512 + wh0);
      float cf[8];
      cf[0] = us2f(cv.x & 0xffffu); cf[1] = us2f(cv.x >> 16);
      cf[2] = us2f(cv.y & 0xffffu); cf[3] = us2f(cv.y >> 16);
      cf[4] = us2f(cv.z & 0xffffu); cf[5] = us2f(cv.z >> 16);
      cf[6] = us2f(cv.w & 0xffffu); cf[7] = us2f(cv.w >> 16);
      uint32_t hb[4];
      #pragma unroll
      for (int k = 0; k < 8; ++k){
        float vv = lrelu(fmaf(cf[k], sc, sh));
        uint32_t bits = (uint32_t)f2bu(vv);
        if ((k & 1) == 0) hb[k >> 1] = bits; else hb[k >> 1] |= bits << 16;
      }
      hv.x = hb[0]; hv.y = hb[1]; hv.z = hb[2]; hv.w = hb[3];
    }
    *(uint4*)&strip[si][wh0] = hv;
  }
  __syncthreads();

  float wf[9];
  #pragma unroll
  for (int i = 0; i < 9; ++i) wf[i] = dw[f * 9 + i];
  float s1 = 0.0f, q1 = 0.0f;
  {
    int si = 1 + (tid >> 6);
    float v[3][10];
    #pragma unroll
    for (int dy = 0; dy < 3; ++dy)
      load_row10(&strip[si - 1 + dy][0], w0, v[dy]);
    uint32_t cb[4];
    #pragma unroll
    for (int k = 0; k < 8; ++k){
      float acc = 0.0f;
      #pragma unroll
      for (int dy = 0; dy < 3; ++dy)
        #pragma unroll
        for (int dx = 0; dx < 3; ++dx)
          acc = fmaf(wf[dy*3 + dx], v[dy][k + dx], acc);
      s1 += acc; q1 += acc * acc;
      uint32_t bits = (uint32_t)f2bu(acc);
      if ((k & 1) == 0) cb[k >> 1] = bits; else cb[k >> 1] |= bits << 16;
    }
    if (write_c){
      uint4 cv2; cv2.x = cb[0]; cv2.y = cb[1]; cv2.z = cb[2]; cv2.w = cb[3];
      *(uint4*)((ushort*)cout + plane * HW + h * 512 + w0) = cv2;
    }
  }

  #pragma unroll
  for (int off = 32; off >= 1; off >>= 1){
    s2 += __shfl_xor(s2, off);
    q2 += __shfl_xor(q2, off);
    s1 += __shfl_xor(s1, off);
    q1 += __shfl_xor(q1, off);
  }
  if ((tid & 63) == 0){
    atomicAdd(&acc4[0], s2); atomicAdd(&acc4[1], q2);
    atomicAdd(&acc4[2], s1); atomicAdd(&acc4[3], q1);
  }
  __syncthreads();
  if (tid < 2)      P2out[bid * 2 + tid]       = acc4[tid];
  else if (tid < 4) P1out[bid * 2 + (tid - 2)] = acc4[tid];
}

// ---------------------------------------------------------------------------
// k_fin_all: 80 wdt/hgt param quadruples, one (t,f) pair per wave. grid 20.
// ---------------------------------------------------------------------------
__global__ __launch_bounds__(256) void k_fin_all(const float* __restrict__ P2,
                                                 const float* __restrict__ ww,
                                                 const float* __restrict__ gw,
                                                 const float* __restrict__ bw,
                                                 const float* __restrict__ wh,
                                                 const float* __restrict__ gh,
                                                 const float* __restrict__ bh,
                                                 float* __restrict__ dparams){
  int tid = threadIdx.x;
  int wid = tid >> 6, lane = tid & 63;
  int pair = blockIdx.x * 4 + wid;              // 0..79
  int t = pair >> 4, f = pair & 15;
  double S, Q;
  chan_sum_wave(P2 + t * 8192, f, lane, S, Q);
  if (lane == 0){
    float m = (float)(S / 524288.0);
    float v = (float)(Q / 524288.0) - m * m;
    float sw = ww[f] * gw[f] / sqrtf(ww[f] * ww[f] * v + EPSF);
    float tw = bw[f] - m * sw;
    float s2 = wh[f] * gh[f] / sqrtf(wh[f] * wh[f] * v + EPSF);
    float t2 = bh[f] - m * s2;
    dparams[t * 64 + f]      = sw;
    dparams[t * 64 + 16 + f] = tw;
    dparams[t * 64 + 32 + f] = s2;
    dparams[t * 64 + 48 + f] = t2;
  }
}

// ---------------------------------------------------------------------------
// F: assemble out. 8 px/thread; all 12 uint4 loads up-front; d_t recomputed
// on the fly from c_t and the saved (sc_t, sh_t).
// ---------------------------------------------------------------------------
__device__ __forceinline__ void conv8(uint4 cc, float* v){
  v[0] = us2f(cc.x & 0xffffu); v[1] = us2f(cc.x >> 16);
  v[2] = us2f(cc.y & 0xffffu); v[3] = us2f(cc.y >> 16);
  v[4] = us2f(cc.z & 0xffffu); v[5] = us2f(cc.z >> 16);
  v[6] = us2f(cc.w & 0xffffu); v[7] = us2f(cc.w >> 16);
}

__global__ __launch_bounds__(256) void k_final(const bf16* __restrict__ p,
                                               const bf16* __restrict__ c1,
                                               const bf16* __restrict__ c2,
                                               const bf16* __restrict__ c3,
                                               const bf16* __restrict__ c4,
                                               const bf16* __restrict__ c5,
                                               const float* __restrict__ dparams,
                                               float* __restrict__ out){
  int tid = threadIdx.x;
  int f = blockIdx.x >> 7;                      // 128 blocks per f
  int gid = blockIdx.x * 256 + tid;             // 0 .. 524287
  int hw = (gid & 32767) << 3;
  int fo = f * HW + hw;
  int f1 = (16 + f) * HW + hw;

  uint4 rp0 = *(const uint4*)((const ushort*)p + fo);
  uint4 rp1 = *(const uint4*)((const ushort*)p + f1);
  uint4 r0a = *(const uint4*)((const ushort*)c1 + fo);
  uint4 r0b = *(const uint4*)((const ushort*)c1 + f1);
  uint4 r1a = *(const uint4*)((const ushort*)c2 + fo);
  uint4 r1b = *(const uint4*)((const ushort*)c2 + f1);
  uint4 r2a = *(const uint4*)((const ushort*)c3 + fo);
  uint4 r2b = *(const uint4*)((const ushort*)c3 + f1);
  uint4 r3a = *(const uint4*)((const ushort*)c4 + fo);
  uint4 r3b = *(const uint4*)((const ushort*)c4 + f1);
  uint4 r4a = *(const uint4*)((const ushort*)c5 + fo);
  uint4 r4b = *(const uint4*)((const ushort*)c5 + f1);

  float swA[5], twA[5], shA[5], thA[5], scA[5], sbA[5];
  #pragma unroll
  for (int t = 0; t < 5; ++t){
    swA[t] = dparams[t * 64 + f];
    twA[t] = dparams[t * 64 + 16 + f];
    shA[t] = dparams[t * 64 + 32 + f];
    thA[t] = dparams[t * 64 + 48 + f];
    scA[t] = dparams[512 + t * 32 + 2 * f];
    sbA[t] = dparams[512 + t * 32 + 2 * f + 1];
  }

  float pf[8], pg[8];
  conv8(rp0, pf); conv8(rp1, pg);
  float a00[8], a01[8], a10[8], a11[8];
  #pragma unroll
  for (int k = 0; k < 8; ++k){ a00[k] = pf[k]; a01[k] = pg[k]; a10[k] = pf[k]; a11[k] = pg[k]; }

  uint4 ra[5] = { r0a, r1a, r2a, r3a, r4a };
  uint4 rb[5] = { r0b, r1b, r2b, r3b, r4b };
  #pragma unroll
  for (int t = 0; t < 5; ++t){
    float cv0[8], cv1[8];
    conv8(ra[t], cv0); conv8(rb[t], cv1);
    float sw = swA[t], tw = twA[t], sh = shA[t], th = thA[t];
    float sc = scA[t], sb = sbA[t];
    #pragma unroll
    for (int k = 0; k < 8; ++k){
      float dv0 = lrelu(fmaf(cv0[k], sc, sb));
      float dv1 = lrelu(fmaf(cv1[k], sc, sb));
      a00[k] += lrelu(fmaf(dv0, sw, tw));
      a01[k] += lrelu(fmaf(dv0, sh, th));
      a10[k] += lrelu(fmaf(dv1, sw, tw));
      a11[k] += lrelu(fmaf(dv1, sh, th));
    }
  }
  #pragma unroll
  for (int half = 0; half < 2; ++half){
    float4 v0 = { a00[half*4+0], a00[half*4+1], a00[half*4+2], a00[half*4+3] };
    float4 v1 = { a01[half*4+0], a01[half*4+1], a01[half*4+2], a01[half*4+3] };
    float4 v2 = { a10[half*4+0], a10[half*4+1], a10[half*4+2], a10[half*4+3] };
    float4 v3 = { a11[half*4+0], a11[half*4+1], a11[half*4+2], a11[half*4+3] };
    *(float4*)(out + f * HW + hw + half*4)        = v0;
    *(float4*)(out + (16 + f) * HW + hw + half*4) = v1;
    *(float4*)(out + (32 + f) * HW + hw + half*4) = v2;
    *(float4*)(out + (48 + f) * HW + hw + half*4) = v3;
  }
}

// ---------------------------------------------------------------------------
extern "C" void kernel_launch(void* const* d_in, const int* in_sizes, int n_in,
                              void* d_out, int out_size, void* d_ws, size_t ws_size,
                              hipStream_t stream){
  (void)in_sizes; (void)n_in; (void)out_size;
  const float* x   = (const float*)d_in[0];
  const float* w1  = (const float*)d_in[1];
  const float* b1  = (const float*)d_in[2];
  const float* g1  = (const float*)d_in[3];
  const float* be1 = (const float*)d_in[4];
  const float* w2  = (const float*)d_in[5];
  const float* b2  = (const float*)d_in[6];
  const float* g2  = (const float*)d_in[7];
  const float* be2 = (const float*)d_in[8];
  const float* dw  = (const float*)d_in[9];
  const float* gd  = (const float*)d_in[10];
  const float* bd  = (const float*)d_in[11];
  const float* ww  = (const float*)d_in[12];
  const float* gw  = (const float*)d_in[13];
  const float* bw  = (const float*)d_in[14];
  const float* wh  = (const float*)d_in[15];
  const float* gh  = (const float*)d_in[16];
  const float* bh  = (const float*)d_in[17];
  float* out = (float*)d_out;

  char* ws = (char*)d_ws;
  size_t off = 0;
  auto alloc = [&](size_t sz) -> void* {
    void* ptr = ws + off;
    off = (off + sz + 4095) & ~(size_t)4095;
    return ptr;
  };
  uint8_t* xm    = (uint8_t*)alloc((size_t)6 * HW);
  bf16*    p     = (bf16*)   alloc((size_t)32 * HW * 2);
  bf16*    cbuf[5];
  for (int i = 0; i < 5; ++i) cbuf[i] = (bf16*)alloc((size_t)32 * HW * 2);
  float*   Pp1    = (float*)  alloc((size_t)512 * 32 * 4);
  float*   Pp2    = (float*)  alloc((size_t)512 * 32 * 4);
  float*   P1a    = (float*)  alloc((size_t)4096 * 2 * 4);
  float*   P1b    = (float*)  alloc((size_t)4096 * 2 * 4);
  float*   P2     = (float*)  alloc((size_t)5 * 4096 * 2 * 4);
  float*   dparams= (float*)  alloc(4096);
  if (ws_size < off) return;   // workspace too small: fail visibly (untouched out)

  k_mode     <<<dim3(768), dim3(256), 0, stream>>>(x, xm);
  k_stats1   <<<dim3(512), dim3(256), 0, stream>>>(xm, w1, b1, Pp1);
  k_stats2   <<<dim3(512), dim3(256), 0, stream>>>(xm, w1, b1, w2, b2,
                                                   Pp1, g1, be1, Pp2);
  k_prep     <<<dim3(512), dim3(256), 0, stream>>>(xm, w1, b1, w2, b2,
                                                   Pp1, g1, be1, Pp2, g2, be2, p);
  k_convstat <<<dim3(4096), dim3(256), 0, stream>>>(p, dw, P1a, cbuf[0]);

  float* Pin = P1a; float* Pout = P1b;
  for (int t = 0; t < 5; ++t){
    k_bnfused<<<dim3(4096), dim3(256), 0, stream>>>(
        cbuf[t], dw, gd, bd, Pin,
        (t < 4) ? cbuf[t + 1] : cbuf[0],      // dummy target when !write_c
        P2 + t * 8192, Pout, dparams, t, (t < 4) ? 1 : 0);
    float* tmp = Pin; Pin = Pout; Pout = tmp;
  }
  k_fin_all<<<dim3(20), dim3(256), 0, stream>>>(P2, ww, gw, bw, wh, gh, bh, dparams);
  k_final<<<dim3(2048), dim3(256), 0, stream>>>(p, cbuf[0], cbuf[1], cbuf[2],
                                                cbuf[3], cbuf[4], dparams, out);
}

// Round 14
// 200.681 us; speedup vs baseline: 4.0483x; 1.0481x over previous
//
#include <hip/hip_runtime.h>
#include <hip/hip_bf16.h>
#include <stdint.h>
#include <stddef.h>

#define HW 262144          // 512*512
#define EPSF 1e-5f

typedef __hip_bfloat16 bf16;

__device__ __forceinline__ float us2f(uint32_t u){
  union { uint32_t i; float f; } c; c.i = u << 16; return c.f;
}
__device__ __forceinline__ ushort f2bu(float v){
  union { bf16 h; ushort u; } c; c.h = __float2bfloat16(v); return c.u;
}
__device__ __forceinline__ float lrelu(float v){ return v > 0.0f ? v : 0.01f * v; }
__device__ __forceinline__ uint32_t umax2(uint32_t a, uint32_t b){ return a > b ? a : b; }

// ---------------------------------------------------------------------------
// K0: 11x11 mode filter with FUSED quantize+reflect-pad staging (vectorized).
// Tile layout: padded col pw (0..521) lives at byte 3+pw => interior (pw>=5,
// ws=pw-5 in 0..511) starts at byte 8 -> dword-aligned u32 stores of 4 packed
// quantized bytes. Halo (pw 0..4, 517..521) staged as 140 scalar bytes.
// Histogram: per-thread sliding 17-bin packed 8-bit in 5 u32 regs (rolled
// loops to avoid the r3/r4 VGPR spill). Grid 768 x 256.
// ---------------------------------------------------------------------------
__global__ __launch_bounds__(256) void k_mode(const float* __restrict__ x,
                                              uint8_t* __restrict__ xm){
  __shared__ uint8_t tile[14 * 528];
  int tid = threadIdx.x;
  int img = blockIdx.x >> 7;
  int h0  = (blockIdx.x & 127) << 2;          // first output row of block
  {
    const float* xp = x + img * HW;
    // interior: 14 rows x 128 dwords (ws = 4*g), one u32 store each
    #pragma unroll 1
    for (int idx = tid; idx < 14 * 128; idx += 256){
      int r = idx >> 7, g = idx & 127;
      int hs = h0 + r - 5; hs = hs < 0 ? -hs : hs; if (hs > 511) hs = 1022 - hs;
      int ws = g << 2;
      float4 v = *(const float4*)(xp + hs * 512 + ws);
      uint32_t b0 = (uint32_t)(uint8_t)(int)rintf((v.x * 255.0f) / 16.0f);
      uint32_t b1 = (uint32_t)(uint8_t)(int)rintf((v.y * 255.0f) / 16.0f);
      uint32_t b2 = (uint32_t)(uint8_t)(int)rintf((v.z * 255.0f) / 16.0f);
      uint32_t b3 = (uint32_t)(uint8_t)(int)rintf((v.w * 255.0f) / 16.0f);
      *(uint32_t*)&tile[r * 528 + 8 + ws] = b0 | (b1 << 8) | (b2 << 16) | (b3 << 24);
    }
    // halo: 14 rows x 10 cols (pw 0..4 and 517..521), scalar bytes
    if (tid < 140){
      int r = tid / 10, i = tid % 10;
      int pw = (i < 5) ? i : (512 + i);      // 0..4 or 517..521
      int hs = h0 + r - 5; hs = hs < 0 ? -hs : hs; if (hs > 511) hs = 1022 - hs;
      int ws = pw - 5; ws = ws < 0 ? -ws : ws; if (ws > 511) ws = 1022 - ws;
      float v = xp[hs * 512 + ws];
      tile[r * 528 + 3 + pw] = (uint8_t)(int)rintf((v * 255.0f) / 16.0f);
    }
  }
  __syncthreads();
  int r4 = tid >> 6;                          // row within block 0..3
  int w0 = (tid & 63) << 3;                   // 0..504 (pw reads w0..w0+17)
  const uint8_t* base = tile + r4 * 528 + 3 + w0;
  uint32_t c0 = 0, c1 = 0, c2 = 0, c3 = 0, c4 = 0;
#define HINC(q) { uint32_t inc_ = 1u << (((q) & 3u) << 3); uint32_t rr_ = (q) >> 2; \
    c0 += (rr_==0u)?inc_:0u; c1 += (rr_==1u)?inc_:0u; c2 += (rr_==2u)?inc_:0u; \
    c3 += (rr_==3u)?inc_:0u; c4 += (rr_==4u)?inc_:0u; }
#define HDEC(q) { uint32_t inc_ = 1u << (((q) & 3u) << 3); uint32_t rr_ = (q) >> 2; \
    c0 -= (rr_==0u)?inc_:0u; c1 -= (rr_==1u)?inc_:0u; c2 -= (rr_==2u)?inc_:0u; \
    c3 -= (rr_==3u)?inc_:0u; c4 -= (rr_==4u)?inc_:0u; }
  #pragma unroll 1
  for (int r = 0; r < 11; ++r){
    const uint8_t* row = base + r * 528;
    #pragma unroll
    for (int j = 0; j < 11; ++j){ uint32_t q = row[j]; HINC(q); }
  }
  uint64_t packed = 0;
  #pragma unroll 1
  for (int s = 0; s < 8; ++s){
    // key(l) = (cnt<<5) | (16-l); max key -> max cnt, tie -> smallest level
#define KEY(reg, sh, l) (((((reg) >> (sh)) & 0xffu) << 5) | (16u - (uint32_t)(l)))
    uint32_t m0 = umax2(umax2(KEY(c0,0,0),  KEY(c0,8,1)),  umax2(KEY(c0,16,2),  KEY(c0,24,3)));
    uint32_t m1 = umax2(umax2(KEY(c1,0,4),  KEY(c1,8,5)),  umax2(KEY(c1,16,6),  KEY(c1,24,7)));
    uint32_t m2 = umax2(umax2(KEY(c2,0,8),  KEY(c2,8,9)),  umax2(KEY(c2,16,10), KEY(c2,24,11)));
    uint32_t m3 = umax2(umax2(KEY(c3,0,12), KEY(c3,8,13)), umax2(KEY(c3,16,14), KEY(c3,24,15)));
    uint32_t m  = umax2(umax2(umax2(m0, m1), umax2(m2, m3)), KEY(c4,0,16));
#undef KEY
    uint32_t lvl = 16u - (m & 31u);
    packed |= ((uint64_t)lvl) << (8 * s);
    if (s < 7){
      #pragma unroll
      for (int r = 0; r < 11; ++r){
        uint32_t qo = base[r * 528 + s];      HDEC(qo);
        uint32_t qn = base[r * 528 + s + 11]; HINC(qn);
      }
    }
  }
#undef HINC
#undef HDEC
  *(uint64_t*)(xm + img * HW + (h0 + r4) * 512 + w0) = packed;
}

// ---------------------------------------------------------------------------
// block reduction of per-thread su[16]/sq[16] -> partials[block][32]
// ---------------------------------------------------------------------------
__device__ __forceinline__ void reduce16(float* su, float* sq, float* __restrict__ partials){
  __shared__ float lsum[32];
  int tid = threadIdx.x;
  if (tid < 32) lsum[tid] = 0.0f;
  __syncthreads();
  #pragma unroll
  for (int o = 0; o < 16; ++o){
    float s = su[o], q = sq[o];
    #pragma unroll
    for (int off = 32; off >= 1; off >>= 1){
      s += __shfl_xor(s, off);
      q += __shfl_xor(q, off);
    }
    if ((tid & 63) == 0){ atomicAdd(&lsum[o], s); atomicAdd(&lsum[16 + o], q); }
  }
  __syncthreads();
  if (tid < 32) partials[blockIdx.x * 32 + tid] = lsum[tid];
}

// ---------------------------------------------------------------------------
// per-block BN-param computation from a [512][32] partials buffer.
// Fully unrolled 4-accumulator load sweep; fixed combine order ->
// bit-identical (sc,sh) in every block. ~64KB/block from L2.
// ---------------------------------------------------------------------------
__device__ __forceinline__ void prep_params(const float* __restrict__ Pp,
                                            const float* __restrict__ g,
                                            const float* __restrict__ bb,
                                            float* prm, float* partS, double* totS){
  int tid = threadIdx.x;
  int o = tid & 31, gg = tid >> 5;            // 8 groups x 32 outputs
  float s0 = 0.0f, s1 = 0.0f, s2 = 0.0f, s3 = 0.0f;
  #pragma unroll
  for (int j = 0; j < 64; j += 4){
    s0 += Pp[(gg * 64 + j    ) * 32 + o];
    s1 += Pp[(gg * 64 + j + 1) * 32 + o];
    s2 += Pp[(gg * 64 + j + 2) * 32 + o];
    s3 += Pp[(gg * 64 + j + 3) * 32 + o];
  }
  partS[gg * 32 + o] = (s0 + s1) + (s2 + s3);
  __syncthreads();
  if (tid < 32){
    double t = 0.0;
    #pragma unroll
    for (int k = 0; k < 8; ++k) t += (double)partS[k * 32 + tid];
    totS[tid] = t;
  }
  __syncthreads();
  if (tid < 16){
    double m = totS[tid] / 524288.0;
    double v = totS[16 + tid] / 524288.0 - m * m;
    float sc = g[tid] / sqrtf((float)v + EPSF);
    prm[tid] = sc;
    prm[16 + tid] = bb[tid] - (float)m * sc;
  }
  __syncthreads();
}

// ---------------------------------------------------------------------------
// K1: stats of p1 = conv1x1(xm). 4 px/thread. grid 512 x 256. -> Pp1
// ---------------------------------------------------------------------------
__global__ __launch_bounds__(256) void k_stats1(const uint8_t* __restrict__ xm,
                                                const float* __restrict__ w1,
                                                const float* __restrict__ b1,
                                                float* __restrict__ partials){
  int t0 = (blockIdx.x * 256 + threadIdx.x) << 2;
  int b = t0 >> 18, hw = t0 & (HW - 1);
  uint32_t q0 = *(const uint32_t*)(xm + (b * 3 + 0) * HW + hw);
  uint32_t q1 = *(const uint32_t*)(xm + (b * 3 + 1) * HW + hw);
  uint32_t q2 = *(const uint32_t*)(xm + (b * 3 + 2) * HW + hw);
  float su[16], sq[16];
  #pragma unroll
  for (int o = 0; o < 16; ++o){ su[o] = 0.0f; sq[o] = 0.0f; }
  #pragma unroll
  for (int px = 0; px < 4; ++px){
    float x0 = (float)((q0 >> (8 * px)) & 0xffu) * 0.0625f;
    float x1 = (float)((q1 >> (8 * px)) & 0xffu) * 0.0625f;
    float x2 = (float)((q2 >> (8 * px)) & 0xffu) * 0.0625f;
    #pragma unroll
    for (int o = 0; o < 16; ++o){
      float v = b1[o] + w1[o*3]*x0 + w1[o*3+1]*x1 + w1[o*3+2]*x2;
      su[o] += v; sq[o] += v * v;
    }
  }
  reduce16(su, sq, partials);
}

// ---------------------------------------------------------------------------
// K2: prologue computes bn1 params from Pp1 (parallel loads); recompute p1,
// bn1+lrelu, p2 = conv1x1, stats -> Pp2 (separate buffer, no race).
// ---------------------------------------------------------------------------
__global__ __launch_bounds__(256) void k_stats2(const uint8_t* __restrict__ xm,
                                                const float* __restrict__ w1,
                                                const float* __restrict__ b1,
                                                const float* __restrict__ w2,
                                                const float* __restrict__ b2,
                                                const float* __restrict__ Pp1,
                                                const float* __restrict__ g1,
                                                const float* __restrict__ be1,
                                                float* __restrict__ Pp2){
  __shared__ float prm[32];
  __shared__ float partS[8 * 32];
  __shared__ double totS[32];
  prep_params(Pp1, g1, be1, prm, partS, totS);
  int t0 = (blockIdx.x * 256 + threadIdx.x) << 2;
  int b = t0 >> 18, hw = t0 & (HW - 1);
  uint32_t q0 = *(const uint32_t*)(xm + (b * 3 + 0) * HW + hw);
  uint32_t q1 = *(const uint32_t*)(xm + (b * 3 + 1) * HW + hw);
  uint32_t q2 = *(const uint32_t*)(xm + (b * 3 + 2) * HW + hw);
  float tv[4][16];
  #pragma unroll
  for (int px = 0; px < 4; ++px){
    float x0 = (float)((q0 >> (8 * px)) & 0xffu) * 0.0625f;
    float x1 = (float)((q1 >> (8 * px)) & 0xffu) * 0.0625f;
    float x2 = (float)((q2 >> (8 * px)) & 0xffu) * 0.0625f;
    #pragma unroll
    for (int o = 0; o < 16; ++o){
      float v = b1[o] + w1[o*3]*x0 + w1[o*3+1]*x1 + w1[o*3+2]*x2;
      tv[px][o] = lrelu(v * prm[o] + prm[16 + o]);
    }
  }
  float su[16], sq[16];
  #pragma unroll
  for (int o = 0; o < 16; ++o){ su[o] = 0.0f; sq[o] = 0.0f; }
  #pragma unroll
  for (int o = 0; o < 16; ++o){
    #pragma unroll
    for (int px = 0; px < 4; ++px){
      float acc = b2[o];
      #pragma unroll
      for (int c = 0; c < 16; ++c) acc = fmaf(w2[o*16 + c], tv[px][c], acc);
      su[o] += acc; sq[o] += acc * acc;
    }
  }
  reduce16(su, sq, Pp2);
}

// ---------------------------------------------------------------------------
// K3: prologue computes bn1 (Pp1) + bn2 (Pp2) params; recompute p2,
// bn2+lrelu, write p (bf16). 4 px/thread.
// ---------------------------------------------------------------------------
__global__ __launch_bounds__(256) void k_prep(const uint8_t* __restrict__ xm,
                                              const float* __restrict__ w1,
                                              const float* __restrict__ b1,
                                              const float* __restrict__ w2,
                                              const float* __restrict__ b2,
                                              const float* __restrict__ Pp1,
                                              const float* __restrict__ g1,
                                              const float* __restrict__ be1,
                                              const float* __restrict__ Pp2,
                                              const float* __restrict__ g2,
                                              const float* __restrict__ be2,
                                              bf16* __restrict__ p){
  __shared__ float prm1[32], prm2[32];
  __shared__ float partS[8 * 32];
  __shared__ double totS[32];
  prep_params(Pp1, g1, be1, prm1, partS, totS);
  prep_params(Pp2, g2, be2, prm2, partS, totS);
  int t0 = (blockIdx.x * 256 + threadIdx.x) << 2;
  int b = t0 >> 18, hw = t0 & (HW - 1);
  uint32_t q0 = *(const uint32_t*)(xm + (b * 3 + 0) * HW + hw);
  uint32_t q1 = *(const uint32_t*)(xm + (b * 3 + 1) * HW + hw);
  uint32_t q2 = *(const uint32_t*)(xm + (b * 3 + 2) * HW + hw);
  float tv[4][16];
  #pragma unroll
  for (int px = 0; px < 4; ++px){
    float x0 = (float)((q0 >> (8 * px)) & 0xffu) * 0.0625f;
    float x1 = (float)((q1 >> (8 * px)) & 0xffu) * 0.0625f;
    float x2 = (float)((q2 >> (8 * px)) & 0xffu) * 0.0625f;
    #pragma unroll
    for (int o = 0; o < 16; ++o){
      float v = b1[o] + w1[o*3]*x0 + w1[o*3+1]*x1 + w1[o*3+2]*x2;
      tv[px][o] = lrelu(v * prm1[o] + prm1[16 + o]);
    }
  }
  #pragma unroll
  for (int o = 0; o < 16; ++o){
    uint32_t w01 = 0, w23 = 0;
    #pragma unroll
    for (int px = 0; px < 4; ++px){
      float acc = b2[o];
      #pragma unroll
      for (int c = 0; c < 16; ++c) acc = fmaf(w2[o*16 + c], tv[px][c], acc);
      float v = lrelu(acc * prm2[o] + prm2[16 + o]);
      uint32_t bits = (uint32_t)f2bu(v);
      if (px == 0) w01 = bits;
      else if (px == 1) w01 |= bits << 16;
      else if (px == 2) w23 = bits;
      else w23 |= bits << 16;
    }
    uint2 ov; ov.x = w01; ov.y = w23;
    *(uint2*)((ushort*)p + (b * 16 + o) * HW + hw) = ov;
  }
}

// ---------------------------------------------------------------------------
// row loader for depthwise conv: 10 values (cols w0-1 .. w0+8), zero-padded.
// ---------------------------------------------------------------------------
__device__ __forceinline__ void load_row10(const ushort* __restrict__ rp, int w0, float* v){
  uint4 cc = *(const uint4*)(rp + w0);
  uint32_t l = (w0 == 0)   ? 0u : (uint32_t)rp[w0 - 1];
  uint32_t r = (w0 == 504) ? 0u : (uint32_t)rp[w0 + 8];
  v[0] = us2f(l);
  v[1] = us2f(cc.x & 0xffffu); v[2] = us2f(cc.x >> 16);
  v[3] = us2f(cc.y & 0xffffu); v[4] = us2f(cc.y >> 16);
  v[5] = us2f(cc.z & 0xffffu); v[6] = us2f(cc.z >> 16);
  v[7] = us2f(cc.w & 0xffffu); v[8] = us2f(cc.w >> 16);
  v[9] = us2f(r);
}

__device__ __forceinline__ void zero_row10(float* v){
  #pragma unroll
  for (int j = 0; j < 10; ++j) v[j] = 0.0f;
}

__device__ __forceinline__ void reduce2(float s, float q, float* __restrict__ partials){
  __shared__ float l2[2];
  int tid = threadIdx.x;
  if (tid < 2) l2[tid] = 0.0f;
  __syncthreads();
  #pragma unroll
  for (int off = 32; off >= 1; off >>= 1){
    s += __shfl_xor(s, off);
    q += __shfl_xor(q, off);
  }
  if ((tid & 63) == 0){ atomicAdd(&l2[0], s); atomicAdd(&l2[1], q); }
  __syncthreads();
  if (tid < 2) partials[blockIdx.x * 2 + tid] = l2[tid];
}

// ---------------------------------------------------------------------------
// A: conv stats of p + write c0 = conv(p) (bf16). grid 4096.
// ---------------------------------------------------------------------------
__global__ __launch_bounds__(256) void k_convstat(const bf16* __restrict__ d,
                                                  const float* __restrict__ dw,
                                                  float* __restrict__ P1,
                                                  bf16* __restrict__ cout){
  int bid = blockIdx.x;
  int plane = bid >> 7, rg = bid & 127;
  int f = plane & 15;
  int tid = threadIdx.x;
  int h  = (rg << 2) + (tid >> 6);
  int w0 = (tid & 63) << 3;
  const ushort* pl = (const ushort*)d + plane * HW;
  float wf[9];
  #pragma unroll
  for (int i = 0; i < 9; ++i) wf[i] = dw[f * 9 + i];
  float v[3][10];
  #pragma unroll
  for (int dy = 0; dy < 3; ++dy){
    int row = h + dy - 1;
    if ((unsigned)row < 512u) load_row10(pl + row * 512, w0, v[dy]);
    else zero_row10(v[dy]);
  }
  float s = 0.0f, q = 0.0f;
  uint32_t cb[4];
  #pragma unroll
  for (int k = 0; k < 8; ++k){
    float acc = 0.0f;
    #pragma unroll
    for (int dy = 0; dy < 3; ++dy)
      #pragma unroll
      for (int dx = 0; dx < 3; ++dx)
        acc = fmaf(wf[dy*3 + dx], v[dy][k + dx], acc);
    s += acc; q += acc * acc;
    uint32_t bits = (uint32_t)f2bu(acc);
    if ((k & 1) == 0) cb[k >> 1] = bits; else cb[k >> 1] |= bits << 16;
  }
  uint4 cv; cv.x = cb[0]; cv.y = cb[1]; cv.z = cb[2]; cv.w = cb[3];
  *(uint4*)((ushort*)cout + plane * HW + h * 512 + w0) = cv;
  reduce2(s, q, P1);
}

// ---------------------------------------------------------------------------
// wave-parallel channel-f sum of a [32 planes][128 rg][2] partials buffer.
// ---------------------------------------------------------------------------
__device__ __forceinline__ void chan_sum_wave(const float* __restrict__ P, int f, int lane,
                                              double& S, double& Q){
  S = 0.0; Q = 0.0;
  #pragma unroll
  for (int i = 0; i < 4; ++i){
    int e = lane + i * 64;                    // 0..255
    int blk = (((e >> 7) * 16 + f) << 7) + (e & 127);
    S += (double)P[blk * 2];
    Q += (double)P[blk * 2 + 1];
  }
  #pragma unroll
  for (int off = 32; off >= 1; off >>= 1){
    S += __shfl_xor(S, off);
    Q += __shfl_xor(Q, off);
  }
}

// ---------------------------------------------------------------------------
// FUSED loop kernel (c-carry, NO d-store). grid 4096, 256 threads.
// ---------------------------------------------------------------------------
__global__ __launch_bounds__(256) void k_bnfused(const bf16* __restrict__ cin,
                                                 const float* __restrict__ dw,
                                                 const float* __restrict__ gd,
                                                 const float* __restrict__ bd,
                                                 const float* __restrict__ P1in,
                                                 bf16* __restrict__ cout,
                                                 float* __restrict__ P2out,
                                                 float* __restrict__ P1out,
                                                 float* __restrict__ dparams,
                                                 int t, int write_c){
  __shared__ ushort strip[6][512];
  __shared__ float acc4[4];
  int bid = blockIdx.x;
  int plane = bid >> 7, rg = bid & 127;
  int f = plane & 15;
  int tid = threadIdx.x;

  double S, Q;
  chan_sum_wave(P1in, f, tid & 63, S, Q);
  float sc, sh;
  {
    double m = S / 524288.0;
    double v = Q / 524288.0 - m * m;
    sc = gd[f] / sqrtf((float)v + EPSF);
    sh = bd[f] - (float)m * sc;
  }
  if (plane < 16 && rg == 0 && tid == 0){
    dparams[512 + t * 32 + 2 * f]     = sc;
    dparams[512 + t * 32 + 2 * f + 1] = sh;
  }
  if (tid < 4) acc4[tid] = 0.0f;

  int h0 = rg << 2;
  int h  = h0 + (tid >> 6);
  int w0 = (tid & 63) << 3;
  const ushort* cpl = (const ushort*)cin + plane * HW;

  float s2 = 0.0f, q2 = 0.0f;
  {
    uint4 cv = *(const uint4*)(cpl + h * 512 + w0);
    float cf[8];
    cf[0] = us2f(cv.x & 0xffffu); cf[1] = us2f(cv.x >> 16);
    cf[2] = us2f(cv.y & 0xffffu); cf[3] = us2f(cv.y >> 16);
    cf[4] = us2f(cv.z & 0xffffu); cf[5] = us2f(cv.z >> 16);
    cf[6] = us2f(cv.w & 0xffffu); cf[7] = us2f(cv.w >> 16);
    uint32_t ob[4];
    #pragma unroll
    for (int k = 0; k < 8; ++k){
      float vv = lrelu(fmaf(cf[k], sc, sh));
      uint32_t bits = (uint32_t)f2bu(vv);
      if ((k & 1) == 0) ob[k >> 1] = bits; else ob[k >> 1] |= bits << 16;
      s2 += vv; q2 += vv * vv;
    }
    uint4 ov; ov.x = ob[0]; ov.y = ob[1]; ov.z = ob[2]; ov.w = ob[3];
    *(uint4*)&strip[1 + (tid >> 6)][w0] = ov;
  }

  if (tid < 128){
    int hh = (tid < 64) ? (h0 - 1) : (h0 + 4);
    int si = (tid < 64) ? 0 : 5;
    int wh0 = (tid & 63) << 3;
    uint4 hv; hv.x = 0; hv.y = 0; hv.z = 0; hv.w = 0;
    if ((unsigned)hh < 512u){
      uint4 cv = *(const uint4*)(cpl + hh * 512 + wh0);
      float cf[8];
      cf[0] = us2f(cv.x & 0xffffu); cf[1] = us2f(cv.x >> 16);
      cf[2] = us2f(cv.y & 0xffffu); cf[3] = us2f(cv.y >> 16);
      cf[4] = us2f(cv.z & 0xffffu); cf[5] = us2f(cv.z >> 16);
      cf[6] = us2f(cv.w & 0xffffu); cf[7] = us2f(cv.w >> 16);
      uint32_t hb[4];
      #pragma unroll
      for (int k = 0; k < 8; ++k){
        float vv = lrelu(fmaf(cf[k], sc, sh));
        uint32_t bits = (uint32_t)f2bu(vv);
        if ((k & 1) == 0) hb[k >> 1] = bits; else hb[k >> 1] |= bits << 16;
      }
      hv.x = hb[0]; hv.y = hb[1]; hv.z = hb[2]; hv.w = hb[3];
    }
    *(uint4*)&strip[si][wh0] = hv;
  }
  __syncthreads();

  float wf[9];
  #pragma unroll
  for (int i = 0; i < 9; ++i) wf[i] = dw[f * 9 + i];
  float s1 = 0.0f, q1 = 0.0f;
  {
    int si = 1 + (tid >> 6);
    float v[3][10];
    #pragma unroll
    for (int dy = 0; dy < 3; ++dy)
      load_row10(&strip[si - 1 + dy][0], w0, v[dy]);
    uint32_t cb[4];
    #pragma unroll
    for (int k = 0; k < 8; ++k){
      float acc = 0.0f;
      #pragma unroll
      for (int dy = 0; dy < 3; ++dy)
        #pragma unroll
        for (int dx = 0; dx < 3; ++dx)
          acc = fmaf(wf[dy*3 + dx], v[dy][k + dx], acc);
      s1 += acc; q1 += acc * acc;
      uint32_t bits = (uint32_t)f2bu(acc);
      if ((k & 1) == 0) cb[k >> 1] = bits; else cb[k >> 1] |= bits << 16;
    }
    if (write_c){
      uint4 cv2; cv2.x = cb[0]; cv2.y = cb[1]; cv2.z = cb[2]; cv2.w = cb[3];
      *(uint4*)((ushort*)cout + plane * HW + h * 512 + w0) = cv2;
    }
  }

  #pragma unroll
  for (int off = 32; off >= 1; off >>= 1){
    s2 += __shfl_xor(s2, off);
    q2 += __shfl_xor(q2, off);
    s1 += __shfl_xor(s1, off);
    q1 += __shfl_xor(q1, off);
  }
  if ((tid & 63) == 0){
    atomicAdd(&acc4[0], s2); atomicAdd(&acc4[1], q2);
    atomicAdd(&acc4[2], s1); atomicAdd(&acc4[3], q1);
  }
  __syncthreads();
  if (tid < 2)      P2out[bid * 2 + tid]       = acc4[tid];
  else if (tid < 4) P1out[bid * 2 + (tid - 2)] = acc4[tid];
}

// ---------------------------------------------------------------------------
// k_fin_all: 80 wdt/hgt param quadruples, one (t,f) pair per wave. grid 20.
// ---------------------------------------------------------------------------
__global__ __launch_bounds__(256) void k_fin_all(const float* __restrict__ P2,
                                                 const float* __restrict__ ww,
                                                 const float* __restrict__ gw,
                                                 const float* __restrict__ bw,
                                                 const float* __restrict__ wh,
                                                 const float* __restrict__ gh,
                                                 const float* __restrict__ bh,
                                                 float* __restrict__ dparams){
  int tid = threadIdx.x;
  int wid = tid >> 6, lane = tid & 63;
  int pair = blockIdx.x * 4 + wid;              // 0..79
  int t = pair >> 4, f = pair & 15;
  double S, Q;
  chan_sum_wave(P2 + t * 8192, f, lane, S, Q);
  if (lane == 0){
    float m = (float)(S / 524288.0);
    float v = (float)(Q / 524288.0) - m * m;
    float sw = ww[f] * gw[f] / sqrtf(ww[f] * ww[f] * v + EPSF);
    float tw = bw[f] - m * sw;
    float s2 = wh[f] * gh[f] / sqrtf(wh[f] * wh[f] * v + EPSF);
    float t2 = bh[f] - m * s2;
    dparams[t * 64 + f]      = sw;
    dparams[t * 64 + 16 + f] = tw;
    dparams[t * 64 + 32 + f] = s2;
    dparams[t * 64 + 48 + f] = t2;
  }
}

// ---------------------------------------------------------------------------
// F: assemble out. 8 px/thread; all 12 uint4 loads up-front; d_t recomputed
// on the fly from c_t and the saved (sc_t, sh_t).
// ---------------------------------------------------------------------------
__device__ __forceinline__ void conv8(uint4 cc, float* v){
  v[0] = us2f(cc.x & 0xffffu); v[1] = us2f(cc.x >> 16);
  v[2] = us2f(cc.y & 0xffffu); v[3] = us2f(cc.y >> 16);
  v[4] = us2f(cc.z & 0xffffu); v[5] = us2f(cc.z >> 16);
  v[6] = us2f(cc.w & 0xffffu); v[7] = us2f(cc.w >> 16);
}

__global__ __launch_bounds__(256) void k_final(const bf16* __restrict__ p,
                                               const bf16* __restrict__ c1,
                                               const bf16* __restrict__ c2,
                                               const bf16* __restrict__ c3,
                                               const bf16* __restrict__ c4,
                                               const bf16* __restrict__ c5,
                                               const float* __restrict__ dparams,
                                               float* __restrict__ out){
  int tid = threadIdx.x;
  int f = blockIdx.x >> 7;                      // 128 blocks per f
  int gid = blockIdx.x * 256 + tid;             // 0 .. 524287
  int hw = (gid & 32767) << 3;
  int fo = f * HW + hw;
  int f1 = (16 + f) * HW + hw;

  uint4 rp0 = *(const uint4*)((const ushort*)p + fo);
  uint4 rp1 = *(const uint4*)((const ushort*)p + f1);
  uint4 r0a = *(const uint4*)((const ushort*)c1 + fo);
  uint4 r0b = *(const uint4*)((const ushort*)c1 + f1);
  uint4 r1a = *(const uint4*)((const ushort*)c2 + fo);
  uint4 r1b = *(const uint4*)((const ushort*)c2 + f1);
  uint4 r2a = *(const uint4*)((const ushort*)c3 + fo);
  uint4 r2b = *(const uint4*)((const ushort*)c3 + f1);
  uint4 r3a = *(const uint4*)((const ushort*)c4 + fo);
  uint4 r3b = *(const uint4*)((const ushort*)c4 + f1);
  uint4 r4a = *(const uint4*)((const ushort*)c5 + fo);
  uint4 r4b = *(const uint4*)((const ushort*)c5 + f1);

  float swA[5], twA[5], shA[5], thA[5], scA[5], sbA[5];
  #pragma unroll
  for (int t = 0; t < 5; ++t){
    swA[t] = dparams[t * 64 + f];
    twA[t] = dparams[t * 64 + 16 + f];
    shA[t] = dparams[t * 64 + 32 + f];
    thA[t] = dparams[t * 64 + 48 + f];
    scA[t] = dparams[512 + t * 32 + 2 * f];
    sbA[t] = dparams[512 + t * 32 + 2 * f + 1];
  }

  float pf[8], pg[8];
  conv8(rp0, pf); conv8(rp1, pg);
  float a00[8], a01[8], a10[8], a11[8];
  #pragma unroll
  for (int k = 0; k < 8; ++k){ a00[k] = pf[k]; a01[k] = pg[k]; a10[k] = pf[k]; a11[k] = pg[k]; }

  uint4 ra[5] = { r0a, r1a, r2a, r3a, r4a };
  uint4 rb[5] = { r0b, r1b, r2b, r3b, r4b };
  #pragma unroll
  for (int t = 0; t < 5; ++t){
    float cv0[8], cv1[8];
    conv8(ra[t], cv0); conv8(rb[t], cv1);
    float sw = swA[t], tw = twA[t], sh = shA[t], th = thA[t];
    float sc = scA[t], sb = sbA[t];
    #pragma unroll
    for (int k = 0; k < 8; ++k){
      float dv0 = lrelu(fmaf(cv0[k], sc, sb));
      float dv1 = lrelu(fmaf(cv1[k], sc, sb));
      a00[k] += lrelu(fmaf(dv0, sw, tw));
      a01[k] += lrelu(fmaf(dv0, sh, th));
      a10[k] += lrelu(fmaf(dv1, sw, tw));
      a11[k] += lrelu(fmaf(dv1, sh, th));
    }
  }
  #pragma unroll
  for (int half = 0; half < 2; ++half){
    float4 v0 = { a00[half*4+0], a00[half*4+1], a00[half*4+2], a00[half*4+3] };
    float4 v1 = { a01[half*4+0], a01[half*4+1], a01[half*4+2], a01[half*4+3] };
    float4 v2 = { a10[half*4+0], a10[half*4+1], a10[half*4+2], a10[half*4+3] };
    float4 v3 = { a11[half*4+0], a11[half*4+1], a11[half*4+2], a11[half*4+3] };
    *(float4*)(out + f * HW + hw + half*4)        = v0;
    *(float4*)(out + (16 + f) * HW + hw + half*4) = v1;
    *(float4*)(out + (32 + f) * HW + hw + half*4) = v2;
    *(float4*)(out + (48 + f) * HW + hw + half*4) = v3;
  }
}

// ---------------------------------------------------------------------------
extern "C" void kernel_launch(void* const* d_in, const int* in_sizes, int n_in,
                              void* d_out, int out_size, void* d_ws, size_t ws_size,
                              hipStream_t stream){
  (void)in_sizes; (void)n_in; (void)out_size;
  const float* x   = (const float*)d_in[0];
  const float* w1  = (const float*)d_in[1];
  const float* b1  = (const float*)d_in[2];
  const float* g1  = (const float*)d_in[3];
  const float* be1 = (const float*)d_in[4];
  const float* w2  = (const float*)d_in[5];
  const float* b2  = (const float*)d_in[6];
  const float* g2  = (const float*)d_in[7];
  const float* be2 = (const float*)d_in[8];
  const float* dw  = (const float*)d_in[9];
  const float* gd  = (const float*)d_in[10];
  const float* bd  = (const float*)d_in[11];
  const float* ww  = (const float*)d_in[12];
  const float* gw  = (const float*)d_in[13];
  const float* bw  = (const float*)d_in[14];
  const float* wh  = (const float*)d_in[15];
  const float* gh  = (const float*)d_in[16];
  const float* bh  = (const float*)d_in[17];
  float* out = (float*)d_out;

  char* ws = (char*)d_ws;
  size_t off = 0;
  auto alloc = [&](size_t sz) -> void* {
    void* ptr = ws + off;
    off = (off + sz + 4095) & ~(size_t)4095;
    return ptr;
  };
  uint8_t* xm    = (uint8_t*)alloc((size_t)6 * HW);
  bf16*    p     = (bf16*)   alloc((size_t)32 * HW * 2);
  bf16*    cbuf[5];
  for (int i = 0; i < 5; ++i) cbuf[i] = (bf16*)alloc((size_t)32 * HW * 2);
  float*   Pp1    = (float*)  alloc((size_t)512 * 32 * 4);
  float*   Pp2    = (float*)  alloc((size_t)512 * 32 * 4);
  float*   P1a    = (float*)  alloc((size_t)4096 * 2 * 4);
  float*   P1b    = (float*)  alloc((size_t)4096 * 2 * 4);
  float*   P2     = (float*)  alloc((size_t)5 * 4096 * 2 * 4);
  float*   dparams= (float*)  alloc(4096);
  if (ws_size < off) return;   // workspace too small: fail visibly (untouched out)

  k_mode     <<<dim3(768), dim3(256), 0, stream>>>(x, xm);
  k_stats1   <<<dim3(512), dim3(256), 0, stream>>>(xm, w1, b1, Pp1);
  k_stats2   <<<dim3(512), dim3(256), 0, stream>>>(xm, w1, b1, w2, b2,
                                                   Pp1, g1, be1, Pp2);
  k_prep     <<<dim3(512), dim3(256), 0, stream>>>(xm, w1, b1, w2, b2,
                                                   Pp1, g1, be1, Pp2, g2, be2, p);
  k_convstat <<<dim3(4096), dim3(256), 0, stream>>>(p, dw, P1a, cbuf[0]);

  float* Pin = P1a; float* Pout = P1b;
  for (int t = 0; t < 5; ++t){
    k_bnfused<<<dim3(4096), dim3(256), 0, stream>>>(
        cbuf[t], dw, gd, bd, Pin,
        (t < 4) ? cbuf[t + 1] : cbuf[0],      // dummy target when !write_c
        P2 + t * 8192, Pout, dparams, t, (t < 4) ? 1 : 0);
    float* tmp = Pin; Pin = Pout; Pout = tmp;
  }
  k_fin_all<<<dim3(20), dim3(256), 0, stream>>>(P2, ww, gw, bw, wh, gh, bh, dparams);
  k_final<<<dim3(2048), dim3(256), 0, stream>>>(p, cbuf[0], cbuf[1], cbuf[2],
                                                cbuf[3], cbuf[4], dparams, out);
}